// Round 14
// baseline (313.765 us; speedup 1.0000x reference)
//
#include <hip/hip_runtime.h>
#include <hip/hip_bf16.h>

#define BN   64
#define MAXN 512
#define DIM  512
#define NH   8
#define NS   32
#define NN   32768      // BN*MAXN
#define NE   524288
#define NBLK 256            // histogram blocks
#define EPB  (NE / NBLK)    // 2048 edges per block
#define MP   (2048 * 512)   // one partial slice

typedef __hip_bfloat16 bf16;
using bf16x8 = __attribute__((ext_vector_type(8))) short;   // 8 bf16 (4 VGPRs)
using f32x4  = __attribute__((ext_vector_type(4))) float;

// ---- persistent device scratch ----
__device__ int            g_cnt[NN];
__device__ int            g_off[NN + 1];
__device__ int            g_csr[NE];
__device__ unsigned short g_hist[(long)NBLK * NN];   // 16 MB
__device__ unsigned short g_bpfx[(long)NBLK * NN];   // 16 MB
__device__ float g_dinv[NN];
__device__ bf16  g_xb[NN * DIM];             // 32 MB
__device__ bf16  g_agg[NN * DIM];            // 32 MB
__device__ bf16  g_aggT[NN * DIM];           // 32 MB [b][d][n]
__device__ bf16  g_qf[256 * DIM];            // QF[h*32+s][d]
__device__ bf16  g_wob[DIM * DIM];           // Wo bf16
__device__ bf16  g_wvb[DIM * DIM];           // Wv bf16
__device__ bf16  g_wvo[DIM * 8 * DIM];       // 4 MB [e][h*512+d]
__device__ float g_bvo[DIM];
__device__ bf16  g_wffT[DIM * DIM];
__device__ float g_q[NS * DIM];
__device__ bf16  g_sc[BN * 256 * MAXN];      // scores -> P (in-place softmax)
__device__ bf16  g_cp[BN * NS * 8 * DIM];    // ctxpre [b*32+s][h*512+d]
__device__ float g_part[4 * MP];             // split-K partials
__device__ float g_h1[BN * NS * DIM];
__device__ bf16  g_h1b[BN * NS * DIM];

__device__ inline float bf2f(unsigned short u) {
    union { unsigned int i; float f; } x; x.i = ((unsigned int)u) << 16; return x.f;
}

__device__ inline void gll16(const bf16* g, bf16* l) {
    __builtin_amdgcn_global_load_lds(
        (const __attribute__((address_space(1))) void*)g,
        (__attribute__((address_space(3))) void*)l, 16, 0, 0);
}

// ---------------- atomic-free CSR build ----------------
// stage 1: per-block LDS histogram of dst (vectorized zero + packed dump)
__global__ __launch_bounds__(512) void k_hist(const int* __restrict__ dst) {
    __shared__ unsigned int h[NN];               // 128 KB
    int p = blockIdx.x, tid = threadIdx.x;
    for (int i = tid; i < NN / 4; i += 512) ((int4*)h)[i] = make_int4(0, 0, 0, 0);
    __syncthreads();
#pragma unroll
    for (int j = 0; j < EPB / 512; j++) {
        int e = p * EPB + j * 512 + tid;
        atomicAdd(&h[dst[e]], 1u);
    }
    __syncthreads();
    unsigned int* out32 = (unsigned int*)(g_hist + (long)p * NN);
    for (int i = tid; i < NN / 2; i += 512)
        out32[i] = h[2 * i] | (h[2 * i + 1] << 16);
}

// stage 2: per-node-pair prefix across blocks -> bpfx, totals -> cnt, dinv
__global__ __launch_bounds__(256) void k_colscan() {
    int v2 = blockIdx.x * 256 + threadIdx.x;     // bin pair (2*v2, 2*v2+1); grid 64
    const unsigned int* H = (const unsigned int*)g_hist;
    unsigned int* B = (unsigned int*)g_bpfx;
    unsigned int s0 = 0, s1 = 0;
#pragma unroll 8
    for (int p = 0; p < NBLK; p++) {
        unsigned int hh = H[(long)p * (NN / 2) + v2];
        B[(long)p * (NN / 2) + v2] = s0 | (s1 << 16);
        s0 += hh & 0xffffu; s1 += hh >> 16;
    }
    g_cnt[2 * v2] = (int)s0;
    g_cnt[2 * v2 + 1] = (int)s1;
    g_dinv[2 * v2] = rsqrtf(1.0f + (float)s0);
    g_dinv[2 * v2 + 1] = rsqrtf(1.0f + (float)s1);
}

// stage 3: exclusive scan of counts -> offsets
__global__ void k_scan() {
    __shared__ int part[1024];
    int t = threadIdx.x;
    int base = t * 32;
    int loc[32]; int s = 0;
#pragma unroll
    for (int i = 0; i < 32; i++) { loc[i] = g_cnt[base + i]; s += loc[i]; }
    part[t] = s; __syncthreads();
    for (int o = 1; o < 1024; o <<= 1) {
        int v = (t >= o) ? part[t - o] : 0;
        __syncthreads();
        part[t] += v;
        __syncthreads();
    }
    int ex = (t == 0) ? 0 : part[t - 1];
#pragma unroll
    for (int i = 0; i < 32; i++) { g_off[base + i] = ex; ex += loc[i]; }
    if (t == 1023) g_off[NN] = ex;
}

// stage 4: deterministic placement via LDS rank counters (b64 packed init)
__global__ __launch_bounds__(512) void k_fillsort(const int* __restrict__ src,
                                                  const int* __restrict__ dst) {
    __shared__ unsigned int l[NN];               // 128 KB
    int p = blockIdx.x, tid = threadIdx.x;
    const unsigned int* bp32 = (const unsigned int*)(g_bpfx + (long)p * NN);
    for (int i = tid; i < NN / 2; i += 512) {
        unsigned int v = bp32[i];
        uint2 o = make_uint2(v & 0xffffu, v >> 16);
        ((uint2*)l)[i] = o;
    }
    __syncthreads();
#pragma unroll
    for (int j = 0; j < EPB / 512; j++) {
        int e = p * EPB + j * 512 + tid;
        int v = dst[e];
        unsigned int r = atomicAdd(&l[v], 1u);
        g_csr[g_off[v] + r] = src[e];
    }
}

// ---------------- prep: qproj (64 blk) | weight cvt (384) | bvo (2) ----------------
__global__ __launch_bounds__(256) void k_prep(const float* __restrict__ seed,
                                              const float* __restrict__ Wq,
                                              const float* __restrict__ Wo,
                                              const float* __restrict__ Wv,
                                              const float* __restrict__ Wff,
                                              const float* __restrict__ bo,
                                              const float* __restrict__ bv) {
    int blk = blockIdx.x;
    if (blk < 64) {                       // q[s][e] = seed[s].Wq[e] / 8
        int i = blk * 256 + threadIdx.x;
        int s = i >> 9, e = i & 511;
        const float* sr = seed + s * DIM;
        const float* wr = Wq + e * DIM;
        float a0 = 0.f, a1 = 0.f;
        for (int d = 0; d < DIM; d += 8) {
            float4 a = *(const float4*)(sr + d);
            float4 b = *(const float4*)(wr + d);
            float4 c = *(const float4*)(sr + d + 4);
            float4 w = *(const float4*)(wr + d + 4);
            a0 += a.x * b.x + a.y * b.y + a.z * b.z + a.w * b.w;
            a1 += c.x * w.x + c.y * w.y + c.z * w.z + c.w * w.w;
        }
        g_q[i] = (a0 + a1) * 0.125f;
    } else if (blk < 448) {               // f32 -> bf16 weight convert
        long t = (long)(blk - 64) * 256 + threadIdx.x;
        const float* srcp; bf16* dstp; long off;
        if (t < 32768)      { srcp = Wo;  dstp = g_wob;  off = t; }
        else if (t < 65536) { srcp = Wv;  dstp = g_wvb;  off = t - 32768; }
        else                { srcp = Wff; dstp = g_wffT; off = t - 65536; }
        long i = off * 8;
        float4 a = *(const float4*)(srcp + i);
        float4 b = *(const float4*)(srcp + i + 4);
        float v[8] = {a.x, a.y, a.z, a.w, b.x, b.y, b.z, b.w};
        bf16x8 o;
#pragma unroll
        for (int j = 0; j < 8; j++) { bf16 q = __float2bfloat16(v[j]); o[j] = *(short*)&q; }
        *(bf16x8*)(dstp + i) = o;
    } else {                              // bvo[e] = bo[e] + bv . Wo[e]
        int e = (blk - 448) * 256 + threadIdx.x;
        const float* orow = Wo + (long)e * DIM;
        float a0 = 0.f, a1 = 0.f;
        for (int c = 0; c < DIM; c += 8) {
            float4 a = *(const float4*)(bv + c);
            float4 w = *(const float4*)(orow + c);
            float4 xx = *(const float4*)(bv + c + 4);
            float4 u = *(const float4*)(orow + c + 4);
            a0 += a.x * w.x + a.y * w.y + a.z * w.z + a.w * w.w;
            a1 += xx.x * u.x + xx.y * u.y + xx.z * u.z + xx.w * u.w;
        }
        g_bvo[e] = bo[e] + a0 + a1;
    }
}

// ---------------- shared 128x128 MFMA GEMM core (swizzled gll + dbuf) ----------------
__device__ __forceinline__ void gemm128(const bf16* __restrict__ A, long lda,
                                        const bf16* __restrict__ Bt, long ldb,
                                        long row0, long col0, int kbeg, int kend,
                                        bf16 (*As)[128 * 32], bf16 (*Bs)[128 * 32],
                                        f32x4 acc[4][4]) {
    int tid = threadIdx.x;
    int lane = tid & 63, wave = tid >> 6;
    int wr = wave >> 1, wc = wave & 1;
    int fr = lane & 15, fq = lane >> 4;
    int rchunk = (fq ^ ((fr >> 1) & 3)) * 8;
    int u0 = wave * 128 + lane;
    int sr0 = u0 >> 2, sc0 = ((u0 & 3) ^ ((sr0 >> 1) & 3)) * 8;
    int u1 = u0 + 64;
    int sr1 = u1 >> 2, sc1 = ((u1 & 3) ^ ((sr1 >> 1) & 3)) * 8;

    auto stage = [&](int buf, int kt) {
        gll16(A + (row0 + sr0) * lda + kt + sc0, As[buf] + u0 * 8);
        gll16(A + (row0 + sr1) * lda + kt + sc1, As[buf] + u1 * 8);
        gll16(Bt + (col0 + sr0) * ldb + kt + sc0, Bs[buf] + u0 * 8);
        gll16(Bt + (col0 + sr1) * ldb + kt + sc1, Bs[buf] + u1 * 8);
    };

    stage(0, kbeg);
    __syncthreads();
    for (int kt = kbeg; kt < kend; kt += 32) {
        int buf = ((kt - kbeg) >> 5) & 1;
        if (kt + 32 < kend) stage(buf ^ 1, kt + 32);
        bf16x8 af[4], bfv[4];
#pragma unroll
        for (int mi = 0; mi < 4; mi++)
            af[mi] = *(const bf16x8*)(As[buf] + (wr * 64 + mi * 16 + fr) * 32 + rchunk);
#pragma unroll
        for (int ni = 0; ni < 4; ni++)
            bfv[ni] = *(const bf16x8*)(Bs[buf] + (wc * 64 + ni * 16 + fr) * 32 + rchunk);
#pragma unroll
        for (int mi = 0; mi < 4; mi++)
#pragma unroll
            for (int ni = 0; ni < 4; ni++)
                acc[mi][ni] = __builtin_amdgcn_mfma_f32_16x16x32_bf16(af[mi], bfv[ni], acc[mi][ni], 0, 0, 0);
        __syncthreads();
    }
}

#define ACC_INIT                                             \
    f32x4 acc[4][4];                                         \
    _Pragma("unroll")                                        \
    for (int i = 0; i < 4; i++)                              \
        _Pragma("unroll")                                    \
        for (int j = 0; j < 4; j++) acc[i][j] = (f32x4){0.f, 0.f, 0.f, 0.f}; \
    int lane = threadIdx.x & 63, wave = threadIdx.x >> 6;    \
    int wr = wave >> 1, wc = wave & 1;                       \
    int fr = lane & 15, fq = lane >> 4;

// merged: xb (8192 blk) | qf (512) | wvo (128)
__global__ __launch_bounds__(256) void k_xbqf(const float* __restrict__ x,
                                              const float* __restrict__ Wk) {
    __shared__ bf16 As[2][128 * 32];
    __shared__ bf16 Bs[2][128 * 32];
    int blk = blockIdx.x;
    if (blk < 8192) {                     // xb = bf16(x * dinv)
        long i = (long)blk * (256 * 8) + (long)threadIdx.x * 8;
        int node = (int)(i >> 9);
        float w = g_dinv[node];
        float4 a = *(const float4*)(x + i);
        float4 b = *(const float4*)(x + i + 4);
        float v[8] = {a.x, a.y, a.z, a.w, b.x, b.y, b.z, b.w};
        bf16x8 o;
#pragma unroll
        for (int j = 0; j < 8; j++) { bf16 t = __float2bfloat16(v[j] * w); o[j] = *(short*)&t; }
        *(bf16x8*)(g_xb + i) = o;
    } else if (blk < 8704) {              // QF[hs][d]
        int i = (blk - 8192) * 256 + threadIdx.x;
        int hs = i >> 9, d = i & 511;
        int h = hs >> 5, s = hs & 31;
        const float* qr = g_q + s * DIM + h * 64;
        const float* wr = Wk + d * DIM + h * 64;
        float a0 = 0.f, a1 = 0.f;
        for (int t2 = 0; t2 < 64; t2 += 8) {
            float4 a = *(const float4*)(qr + t2);
            float4 w = *(const float4*)(wr + t2);
            float4 c = *(const float4*)(qr + t2 + 4);
            float4 u = *(const float4*)(wr + t2 + 4);
            a0 += a.x * w.x + a.y * w.y + a.z * w.z + a.w * w.w;
            a1 += c.x * u.x + c.y * u.y + c.z * u.z + c.w * u.w;
        }
        g_qf[i] = __float2bfloat16(a0 + a1);
    } else {                              // Wvo GEMM, batched per head (K=64)
        int wi = blk - 8704;
        int bx = wi & 3, by = (wi >> 2) & 3, h = wi >> 4;
        ACC_INIT
        long row0 = (long)bx * 128, col0 = (long)by * 128;
        gemm128(g_wob, DIM, g_wvb, DIM, row0, col0, h * 64, h * 64 + 64, As, Bs, acc);
#pragma unroll
        for (int mi = 0; mi < 4; mi++)
#pragma unroll
            for (int ni = 0; ni < 4; ni++) {
                long col = col0 + wc * 64 + ni * 16 + fr;
#pragma unroll
                for (int r = 0; r < 4; r++) {
                    long row = row0 + wr * 64 + mi * 16 + fq * 4 + r;
                    g_wvo[row * 4096 + h * 512 + col] = __float2bfloat16(acc[mi][ni][r]);
                }
            }
    }
}

// ---------------- LDS-staged SpMM gather: one block per (graph, 64-feat tile) ----------------
// agg[b*512+n][ft*64+f] = dinv[n] * ( xb[b*512+n][.] + sum_{e:src->n} xb[src][.] )
__global__ __launch_bounds__(512) void k_spmm() {
    __shared__ bf16 T[512 * 64];                 // 64 KB : [src&511][feat]
    int blk = blockIdx.x;
    int b = blk & 63, ft = blk >> 6;             // blk%8 == b%8 -> graph pinned to one XCD
    int tid = threadIdx.x;
    const bf16* srcp = g_xb + ((long)b * 512) * 512 + ft * 64;
#pragma unroll
    for (int c = 0; c < 8; c++) {
        int u = tid + 512 * c;
        int row = u >> 3, col = (u & 7) * 8;
        gll16(srcp + (long)row * 512 + col, T + u * 8);
    }
    __syncthreads();

    int w = tid >> 6, lane = tid & 63;
    const unsigned short* Tl = (const unsigned short*)T;
    for (int nl = 0; nl < 64; nl++) {
        int lrow = w * 64 + nl;
        int node = b * 512 + lrow;
        float acc = bf2f(Tl[lrow * 64 + lane]);          // self loop
        int e = g_off[node], e1 = g_off[node + 1];
        for (; e + 2 <= e1; e += 2) {
            int s0 = g_csr[e] & 511, s1 = g_csr[e + 1] & 511;
            float f0 = bf2f(Tl[s0 * 64 + lane]);
            float f1 = bf2f(Tl[s1 * 64 + lane]);
            acc += f0 + f1;
        }
        if (e < e1) acc += bf2f(Tl[(g_csr[e] & 511) * 64 + lane]);
        bf16 q = __float2bfloat16(acc * g_dinv[node]);
        ((unsigned short*)g_agg)[(long)node * 512 + ft * 64 + lane] = *(unsigned short*)&q;
    }
}

// merged: scores (512 blk, graph-major XCD swizzle) | aggT (4096 blk)
__global__ __launch_bounds__(256) void k_aggsc() {
    __shared__ __align__(16) char smem[32768];
    int blk = blockIdx.x;
    if (blk < 512) {                      // scores: C[hs][n] = QF . agg_b^T
        bf16 (*As)[128 * 32] = (bf16(*)[128 * 32])smem;
        bf16 (*Bs)[128 * 32] = (bf16(*)[128 * 32])(smem + 16384);
        int b = blk & 63, bx = (blk >> 6) & 1, by = blk >> 7;
        ACC_INIT
        long row0 = (long)bx * 128, col0 = (long)by * 128;
        gemm128(g_qf, DIM, g_agg + (long)b * (MAXN * DIM), DIM, row0, col0, 0, DIM, As, Bs, acc);
        bf16* out = g_sc + (long)b * (256 * MAXN);
#pragma unroll
        for (int mi = 0; mi < 4; mi++)
#pragma unroll
            for (int ni = 0; ni < 4; ni++) {
                long col = col0 + wc * 64 + ni * 16 + fr;
#pragma unroll
                for (int r = 0; r < 4; r++) {
                    long row = row0 + wr * 64 + mi * 16 + fq * 4 + r;
                    out[row * MAXN + col] = __float2bfloat16(acc[mi][ni][r]);
                }
            }
    } else {                              // aggT[b][d][n] = agg[b*512+n][d]
        unsigned short (*L)[72] = (unsigned short(*)[72])smem;
        int id = blk - 512;
        int b = id >> 6, t = id & 63;
        int n0 = (t & 7) * 64, d0 = (t >> 3) * 64;
        int tid = threadIdx.x;
        const unsigned short* src = (const unsigned short*)g_agg + ((long)b * 512 + n0) * 512 + d0;
#pragma unroll
        for (int p = 0; p < 2; p++) {
            int r = (tid >> 3) + 32 * p, c = (tid & 7) * 8;
            *(int4*)&L[r][c] = *(const int4*)(src + (long)r * 512 + c);
        }
        __syncthreads();
        unsigned short* dst = (unsigned short*)g_aggT + ((long)b * 512 + d0) * 512 + n0;
#pragma unroll
        for (int p = 0; p < 2; p++) {
            int dr = (tid >> 3) + 32 * p, c0 = (tid & 7) * 8;
            unsigned short tmp[8];
#pragma unroll
            for (int j = 0; j < 8; j++) tmp[j] = L[c0 + j][dr];
            *(int4*)(dst + (long)dr * 512 + c0) = *(int4*)tmp;
        }
    }
}

// in-place row softmax on g_sc (16384 rows of 512)
__global__ __launch_bounds__(256) void k_soft() {
    int w = threadIdx.x >> 6, lane = threadIdx.x & 63;
    unsigned short* base = (unsigned short*)g_sc + ((long)blockIdx.x * 16 + w * 4) * MAXN;
#pragma unroll
    for (int r = 0; r < 4; r++) {
        unsigned short* row = base + (long)r * MAXN;
        float v[8]; float m = -1e30f;
#pragma unroll
        for (int k = 0; k < 8; k++) { v[k] = bf2f(row[lane + 64 * k]); m = fmaxf(m, v[k]); }
#pragma unroll
        for (int o = 32; o > 0; o >>= 1) m = fmaxf(m, __shfl_xor(m, o));
        float sum = 0.f;
#pragma unroll
        for (int k = 0; k < 8; k++) { v[k] = __expf(v[k] - m); sum += v[k]; }
#pragma unroll
        for (int o = 32; o > 0; o >>= 1) sum += __shfl_xor(sum, o);
        float inv = 1.0f / sum;
#pragma unroll
        for (int k = 0; k < 8; k++) {
            bf16 t = __float2bfloat16(v[k] * inv);
            row[lane + 64 * k] = *(unsigned short*)&t;
        }
    }
}

// ctxpre: per (b,dh): C[hs][d] = P_b[hs][:] . aggT_b[dh*256+d][:]  (graph-major swizzle)
__global__ __launch_bounds__(256) void k_pvg() {
    __shared__ bf16 As[2][128 * 32];
    __shared__ bf16 Bs[2][128 * 32];
    int blk = blockIdx.x;
    int b = blk & 63, bx = (blk >> 6) & 1, by = (blk >> 7) & 1, dh = blk >> 8;
    ACC_INIT
    long row0 = (long)bx * 128, col0 = (long)by * 128;
    gemm128(g_sc + (long)b * (256 * MAXN), MAXN,
            g_aggT + (long)b * (DIM * MAXN) + (long)dh * (256 * MAXN), MAXN,
            row0, col0, 0, MAXN, As, Bs, acc);
#pragma unroll
    for (int mi = 0; mi < 4; mi++)
#pragma unroll
        for (int ni = 0; ni < 4; ni++) {
            long col = col0 + wc * 64 + ni * 16 + fr;
#pragma unroll
            for (int r = 0; r < 4; r++) {
                long row = row0 + wr * 64 + mi * 16 + fq * 4 + r;   // hs
                g_cp[((long)b * NS + (row & 31)) * 4096 + (row >> 5) * 512 + dh * 256 + col] =
                    __float2bfloat16(acc[mi][ni][r]);
            }
        }
}

// attn_out partials: A=g_cp [2048][4096], Bt=g_wvo [512][4096], 4-way split-K
__global__ __launch_bounds__(256) void k_vo() {
    __shared__ bf16 As[2][128 * 32];
    __shared__ bf16 Bs[2][128 * 32];
    ACC_INIT
    int z = blockIdx.z;
    long row0 = (long)blockIdx.x * 128, col0 = (long)blockIdx.y * 128;
    gemm128(g_cp, 4096, g_wvo, 4096, row0, col0, z * 1024, z * 1024 + 1024, As, Bs, acc);
    float* out = g_part + (long)z * MP;
#pragma unroll
    for (int mi = 0; mi < 4; mi++)
#pragma unroll
        for (int ni = 0; ni < 4; ni++) {
            long col = col0 + wc * 64 + ni * 16 + fr;
#pragma unroll
            for (int r = 0; r < 4; r++) {
                long row = row0 + wr * 64 + mi * 16 + fq * 4 + r;
                out[row * DIM + col] = acc[mi][ni][r];
            }
        }
}

// FFN partials: A=g_h1b [2048][512], Bt=g_wffT [512][512], 4-way split-K
__global__ __launch_bounds__(256) void k_ffn() {
    __shared__ bf16 As[2][128 * 32];
    __shared__ bf16 Bs[2][128 * 32];
    ACC_INIT
    int z = blockIdx.z;
    long row0 = (long)blockIdx.x * 128, col0 = (long)blockIdx.y * 128;
    gemm128(g_h1b, DIM, g_wffT, DIM, row0, col0, z * 128, z * 128 + 128, As, Bs, acc);
    float* out = g_part + (long)z * MP;
#pragma unroll
    for (int mi = 0; mi < 4; mi++)
#pragma unroll
        for (int ni = 0; ni < 4; ni++) {
            long col = col0 + wc * 64 + ni * 16 + fr;
#pragma unroll
            for (int r = 0; r < 4; r++) {
                long row = row0 + wr * 64 + mi * 16 + fq * 4 + r;
                out[row * DIM + col] = acc[mi][ni][r];
            }
        }
}

// ---------------- layernorms (fused split-K reduction + bias) ----------------
__device__ inline float blockReduceSum(float v, float* red, int tid) {
#pragma unroll
    for (int o = 32; o > 0; o >>= 1) v += __shfl_xor(v, o);
    __syncthreads();
    if ((tid & 63) == 0) red[tid >> 6] = v;
    __syncthreads();
    return red[0] + red[1] + red[2] + red[3];
}

__global__ __launch_bounds__(256) void k_ln1(const float* __restrict__ seed,
                                             const float* __restrict__ gamma,
                                             const float* __restrict__ beta) {
    __shared__ float red[4];
    int r = blockIdx.x, t = threadIdx.x;
    int s = r & 31;
    long base = (long)r * DIM;
    float v0 = seed[s * DIM + t] + g_bvo[t];
    float v1 = seed[s * DIM + 256 + t] + g_bvo[256 + t];
#pragma unroll
    for (int z = 0; z < 4; z++) {
        v0 += g_part[(long)z * MP + base + t];
        v1 += g_part[(long)z * MP + base + 256 + t];
    }
    float mean = blockReduceSum(v0 + v1, red, t) * (1.0f / DIM);
    float d0 = v0 - mean, d1 = v1 - mean;
    float var = blockReduceSum(d0 * d0 + d1 * d1, red, t) * (1.0f / DIM);
    float ri = rsqrtf(var + 1e-5f);
    float o0 = d0 * ri * gamma[t] + beta[t];
    float o1 = d1 * ri * gamma[256 + t] + beta[256 + t];
    g_h1[base + t] = o0; g_h1[base + 256 + t] = o1;
    g_h1b[base + t] = __float2bfloat16(o0);
    g_h1b[base + 256 + t] = __float2bfloat16(o1);
}

__global__ __launch_bounds__(256) void k_ln2(const float* __restrict__ gamma,
                                             const float* __restrict__ beta,
                                             const float* __restrict__ bff,
                                             float* __restrict__ out) {
    __shared__ float red[4];
    int r = blockIdx.x, t = threadIdx.x;
    long base = (long)r * DIM;
    float v0 = g_h1[base + t] + bff[t];
    float v1 = g_h1[base + 256 + t] + bff[256 + t];
#pragma unroll
    for (int z = 0; z < 4; z++) {
        v0 += g_part[(long)z * MP + base + t];
        v1 += g_part[(long)z * MP + base + 256 + t];
    }
    float mean = blockReduceSum(v0 + v1, red, t) * (1.0f / DIM);
    float d0 = v0 - mean, d1 = v1 - mean;
    float var = blockReduceSum(d0 * d0 + d1 * d1, red, t) * (1.0f / DIM);
    float ri = rsqrtf(var + 1e-5f);
    out[base + t] = d0 * ri * gamma[t] + beta[t];
    out[base + 256 + t] = d1 * ri * gamma[256 + t] + beta[256 + t];
}

// ---------------- launch ----------------
extern "C" void kernel_launch(void* const* d_in, const int* in_sizes, int n_in,
                              void* d_out, int out_size, void* d_ws, size_t ws_size,
                              hipStream_t stream) {
    (void)in_sizes; (void)n_in; (void)out_size; (void)d_ws; (void)ws_size;
    const float* x    = (const float*)d_in[1];
    const int*   ei   = (const int*)d_in[2];
    const int*   esrc = ei;
    const int*   edst = ei + NE;
    const float* seed = (const float*)d_in[4];
    const float* Wk   = (const float*)d_in[5];
    const float* Wv   = (const float*)d_in[7];
    const float* bv   = (const float*)d_in[8];
    const float* Wq   = (const float*)d_in[9];
    const float* Wo   = (const float*)d_in[10];
    const float* bo   = (const float*)d_in[11];
    const float* Wff  = (const float*)d_in[12];
    const float* bff  = (const float*)d_in[13];
    const float* gh   = (const float*)d_in[14];
    const float* bh   = (const float*)d_in[15];
    const float* gz   = (const float*)d_in[16];
    const float* bz   = (const float*)d_in[17];
    float* out = (float*)d_out;

    k_hist    <<<NBLK, 512, 0, stream>>>(edst);
    k_colscan <<<NN / 512, 256, 0, stream>>>();
    k_scan    <<<1, 1024, 0, stream>>>();
    k_prep    <<<450, 256, 0, stream>>>(seed, Wq, Wo, Wv, Wff, bo, bv);
    k_fillsort<<<NBLK, 512, 0, stream>>>(esrc, edst);
    k_xbqf    <<<8832, 256, 0, stream>>>(x, Wk);
    k_spmm    <<<512, 512, 0, stream>>>();
    k_aggsc   <<<512 + BN * 64, 256, 0, stream>>>();
    k_soft    <<<1024, 256, 0, stream>>>();
    k_pvg     <<<512, 256, 0, stream>>>();
    k_vo      <<<dim3(16, 4, 4), 256, 0, stream>>>();
    k_ln1     <<<BN * NS, 256, 0, stream>>>(seed, gh, bh);
    k_ffn     <<<dim3(16, 4, 4), 256, 0, stream>>>();
    k_ln2     <<<BN * NS, 256, 0, stream>>>(gz, bz, bff, out);
}

// Round 15
// 221.232 us; speedup vs baseline: 1.4183x; 1.4183x over previous
//
#include <hip/hip_runtime.h>
#include <hip/hip_bf16.h>

#define BN   64
#define MAXN 512
#define DIM  512
#define NH   8
#define NS   32
#define NN   32768      // BN*MAXN
#define NE   524288
#define NBLK 256            // histogram blocks
#define EPB  (NE / NBLK)    // 2048 edges per block
#define MP   (2048 * 512)   // one partial slice

typedef __hip_bfloat16 bf16;
using bf16x8 = __attribute__((ext_vector_type(8))) short;   // 8 bf16 (4 VGPRs)
using f32x4  = __attribute__((ext_vector_type(4))) float;

// ---- persistent device scratch ----
__device__ int            g_cnt[NN];
__device__ int            g_off[NN + 1];
__device__ int            g_csr[NE];
__device__ unsigned short g_hist[(long)NBLK * NN];   // 16 MB
__device__ unsigned short g_bpfx[(long)NBLK * NN];   // 16 MB
__device__ float g_dinv[NN];
__device__ bf16  g_xb[NN * DIM];             // 32 MB
__device__ bf16  g_agg[NN * DIM];            // 32 MB
__device__ bf16  g_aggT[NN * DIM];           // 32 MB [b][d][n]
__device__ bf16  g_qf[256 * DIM];            // QF[h*32+s][d]
__device__ bf16  g_wob[DIM * DIM];           // Wo bf16
__device__ bf16  g_wvb[DIM * DIM];           // Wv bf16
__device__ bf16  g_wvo[DIM * 8 * DIM];       // 4 MB [e][h*512+d]
__device__ float g_bvo[DIM];
__device__ bf16  g_wffT[DIM * DIM];
__device__ float g_q[NS * DIM];
__device__ bf16  g_sc[BN * 256 * MAXN];      // scores -> P (in-place softmax)
__device__ bf16  g_cp[BN * NS * 8 * DIM];    // ctxpre [b*32+s][h*512+d]
__device__ float g_part[4 * MP];             // split-K partials
__device__ float g_h1[BN * NS * DIM];
__device__ bf16  g_h1b[BN * NS * DIM];

__device__ inline float bf2f(unsigned short u) {
    union { unsigned int i; float f; } x; x.i = ((unsigned int)u) << 16; return x.f;
}

__device__ inline void gll16(const bf16* g, bf16* l) {
    __builtin_amdgcn_global_load_lds(
        (const __attribute__((address_space(1))) void*)g,
        (__attribute__((address_space(3))) void*)l, 16, 0, 0);
}

// ---------------- atomic-free CSR build ----------------
// stage 1: per-block LDS histogram of dst (1024 thr: 16 waves/CU hides LDS latency)
__global__ __launch_bounds__(1024) void k_hist(const int* __restrict__ dst) {
    __shared__ unsigned int h[NN];               // 128 KB
    int p = blockIdx.x, tid = threadIdx.x;
    for (int i = tid; i < NN / 4; i += 1024) ((int4*)h)[i] = make_int4(0, 0, 0, 0);
    __syncthreads();
#pragma unroll
    for (int j = 0; j < EPB / 1024; j++) {
        int e = p * EPB + j * 1024 + tid;
        atomicAdd(&h[dst[e]], 1u);
    }
    __syncthreads();
    unsigned int* out32 = (unsigned int*)(g_hist + (long)p * NN);
    for (int i = tid; i < NN / 2; i += 1024)
        out32[i] = h[2 * i] | (h[2 * i + 1] << 16);
}

// stage 2: per-node-pair prefix across blocks -> bpfx (packed), totals -> cnt, dinv
__global__ __launch_bounds__(256) void k_colscan() {
    int v2 = blockIdx.x * 256 + threadIdx.x;     // bin pair (2*v2, 2*v2+1); grid 64
    const unsigned int* H = (const unsigned int*)g_hist;
    unsigned int* B = (unsigned int*)g_bpfx;
    unsigned int s0 = 0, s1 = 0;
#pragma unroll 8
    for (int p = 0; p < NBLK; p++) {
        unsigned int hh = H[(long)p * (NN / 2) + v2];
        B[(long)p * (NN / 2) + v2] = s0 | (s1 << 16);
        s0 += hh & 0xffffu; s1 += hh >> 16;
    }
    g_cnt[2 * v2] = (int)s0;
    g_cnt[2 * v2 + 1] = (int)s1;
    g_dinv[2 * v2] = rsqrtf(1.0f + (float)s0);
    g_dinv[2 * v2 + 1] = rsqrtf(1.0f + (float)s1);
}

// stage 3: exclusive scan of counts -> offsets
__global__ void k_scan() {
    __shared__ int part[1024];
    int t = threadIdx.x;
    int base = t * 32;
    int loc[32]; int s = 0;
#pragma unroll
    for (int i = 0; i < 32; i++) { loc[i] = g_cnt[base + i]; s += loc[i]; }
    part[t] = s; __syncthreads();
    for (int o = 1; o < 1024; o <<= 1) {
        int v = (t >= o) ? part[t - o] : 0;
        __syncthreads();
        part[t] += v;
        __syncthreads();
    }
    int ex = (t == 0) ? 0 : part[t - 1];
#pragma unroll
    for (int i = 0; i < 32; i++) { g_off[base + i] = ex; ex += loc[i]; }
    if (t == 1023) g_off[NN] = ex;
}

// stage 4: deterministic placement via LDS rank counters (1024 thr, packed init)
__global__ __launch_bounds__(1024) void k_fillsort(const int* __restrict__ src,
                                                   const int* __restrict__ dst) {
    __shared__ unsigned int l[NN];               // 128 KB
    int p = blockIdx.x, tid = threadIdx.x;
    const unsigned int* bp32 = (const unsigned int*)(g_bpfx + (long)p * NN);
    for (int i = tid; i < NN / 2; i += 1024) {
        unsigned int v = bp32[i];
        ((uint2*)l)[i] = make_uint2(v & 0xffffu, v >> 16);
    }
    __syncthreads();
#pragma unroll
    for (int j = 0; j < EPB / 1024; j++) {
        int e = p * EPB + j * 1024 + tid;
        int v = dst[e];
        unsigned int r = atomicAdd(&l[v], 1u);
        g_csr[g_off[v] + r] = src[e];
    }
}

// ---------------- prep: qproj (64 blk) | weight cvt (384) | bvo (2) ----------------
__global__ __launch_bounds__(256) void k_prep(const float* __restrict__ seed,
                                              const float* __restrict__ Wq,
                                              const float* __restrict__ Wo,
                                              const float* __restrict__ Wv,
                                              const float* __restrict__ Wff,
                                              const float* __restrict__ bo,
                                              const float* __restrict__ bv) {
    int blk = blockIdx.x;
    if (blk < 64) {                       // q[s][e] = seed[s].Wq[e] / 8
        int i = blk * 256 + threadIdx.x;
        int s = i >> 9, e = i & 511;
        const float* sr = seed + s * DIM;
        const float* wr = Wq + e * DIM;
        float a0 = 0.f, a1 = 0.f;
        for (int d = 0; d < DIM; d += 8) {
            float4 a = *(const float4*)(sr + d);
            float4 b = *(const float4*)(wr + d);
            float4 c = *(const float4*)(sr + d + 4);
            float4 w = *(const float4*)(wr + d + 4);
            a0 += a.x * b.x + a.y * b.y + a.z * b.z + a.w * b.w;
            a1 += c.x * w.x + c.y * w.y + c.z * w.z + c.w * w.w;
        }
        g_q[i] = (a0 + a1) * 0.125f;
    } else if (blk < 448) {               // f32 -> bf16 weight convert
        long t = (long)(blk - 64) * 256 + threadIdx.x;
        const float* srcp; bf16* dstp; long off;
        if (t < 32768)      { srcp = Wo;  dstp = g_wob;  off = t; }
        else if (t < 65536) { srcp = Wv;  dstp = g_wvb;  off = t - 32768; }
        else                { srcp = Wff; dstp = g_wffT; off = t - 65536; }
        long i = off * 8;
        float4 a = *(const float4*)(srcp + i);
        float4 b = *(const float4*)(srcp + i + 4);
        float v[8] = {a.x, a.y, a.z, a.w, b.x, b.y, b.z, b.w};
        bf16x8 o;
#pragma unroll
        for (int j = 0; j < 8; j++) { bf16 q = __float2bfloat16(v[j]); o[j] = *(short*)&q; }
        *(bf16x8*)(dstp + i) = o;
    } else {                              // bvo[e] = bo[e] + bv . Wo[e]
        int e = (blk - 448) * 256 + threadIdx.x;
        const float* orow = Wo + (long)e * DIM;
        float a0 = 0.f, a1 = 0.f;
        for (int c = 0; c < DIM; c += 8) {
            float4 a = *(const float4*)(bv + c);
            float4 w = *(const float4*)(orow + c);
            float4 xx = *(const float4*)(bv + c + 4);
            float4 u = *(const float4*)(orow + c + 4);
            a0 += a.x * w.x + a.y * w.y + a.z * w.z + a.w * w.w;
            a1 += xx.x * u.x + xx.y * u.y + xx.z * u.z + xx.w * u.w;
        }
        g_bvo[e] = bo[e] + a0 + a1;
    }
}

// ---------------- shared 128x128 MFMA GEMM core (swizzled gll + dbuf) ----------------
__device__ __forceinline__ void gemm128(const bf16* __restrict__ A, long lda,
                                        const bf16* __restrict__ Bt, long ldb,
                                        long row0, long col0, int kbeg, int kend,
                                        bf16 (*As)[128 * 32], bf16 (*Bs)[128 * 32],
                                        f32x4 acc[4][4]) {
    int tid = threadIdx.x;
    int lane = tid & 63, wave = tid >> 6;
    int wr = wave >> 1, wc = wave & 1;
    int fr = lane & 15, fq = lane >> 4;
    int rchunk = (fq ^ ((fr >> 1) & 3)) * 8;
    int u0 = wave * 128 + lane;
    int sr0 = u0 >> 2, sc0 = ((u0 & 3) ^ ((sr0 >> 1) & 3)) * 8;
    int u1 = u0 + 64;
    int sr1 = u1 >> 2, sc1 = ((u1 & 3) ^ ((sr1 >> 1) & 3)) * 8;

    auto stage = [&](int buf, int kt) {
        gll16(A + (row0 + sr0) * lda + kt + sc0, As[buf] + u0 * 8);
        gll16(A + (row0 + sr1) * lda + kt + sc1, As[buf] + u1 * 8);
        gll16(Bt + (col0 + sr0) * ldb + kt + sc0, Bs[buf] + u0 * 8);
        gll16(Bt + (col0 + sr1) * ldb + kt + sc1, Bs[buf] + u1 * 8);
    };

    stage(0, kbeg);
    __syncthreads();
    for (int kt = kbeg; kt < kend; kt += 32) {
        int buf = ((kt - kbeg) >> 5) & 1;
        if (kt + 32 < kend) stage(buf ^ 1, kt + 32);
        bf16x8 af[4], bfv[4];
#pragma unroll
        for (int mi = 0; mi < 4; mi++)
            af[mi] = *(const bf16x8*)(As[buf] + (wr * 64 + mi * 16 + fr) * 32 + rchunk);
#pragma unroll
        for (int ni = 0; ni < 4; ni++)
            bfv[ni] = *(const bf16x8*)(Bs[buf] + (wc * 64 + ni * 16 + fr) * 32 + rchunk);
#pragma unroll
        for (int mi = 0; mi < 4; mi++)
#pragma unroll
            for (int ni = 0; ni < 4; ni++)
                acc[mi][ni] = __builtin_amdgcn_mfma_f32_16x16x32_bf16(af[mi], bfv[ni], acc[mi][ni], 0, 0, 0);
        __syncthreads();
    }
}

#define ACC_INIT                                             \
    f32x4 acc[4][4];                                         \
    _Pragma("unroll")                                        \
    for (int i = 0; i < 4; i++)                              \
        _Pragma("unroll")                                    \
        for (int j = 0; j < 4; j++) acc[i][j] = (f32x4){0.f, 0.f, 0.f, 0.f}; \
    int lane = threadIdx.x & 63, wave = threadIdx.x >> 6;    \
    int wr = wave >> 1, wc = wave & 1;                       \
    int fr = lane & 15, fq = lane >> 4;

// merged: xb (8192 blk) | qf (512) | wvo (128)
__global__ __launch_bounds__(256) void k_xbqf(const float* __restrict__ x,
                                              const float* __restrict__ Wk) {
    __shared__ bf16 As[2][128 * 32];
    __shared__ bf16 Bs[2][128 * 32];
    int blk = blockIdx.x;
    if (blk < 8192) {                     // xb = bf16(x * dinv)
        long i = (long)blk * (256 * 8) + (long)threadIdx.x * 8;
        int node = (int)(i >> 9);
        float w = g_dinv[node];
        float4 a = *(const float4*)(x + i);
        float4 b = *(const float4*)(x + i + 4);
        float v[8] = {a.x, a.y, a.z, a.w, b.x, b.y, b.z, b.w};
        bf16x8 o;
#pragma unroll
        for (int j = 0; j < 8; j++) { bf16 t = __float2bfloat16(v[j] * w); o[j] = *(short*)&t; }
        *(bf16x8*)(g_xb + i) = o;
    } else if (blk < 8704) {              // QF[hs][d]
        int i = (blk - 8192) * 256 + threadIdx.x;
        int hs = i >> 9, d = i & 511;
        int h = hs >> 5, s = hs & 31;
        const float* qr = g_q + s * DIM + h * 64;
        const float* wr = Wk + d * DIM + h * 64;
        float a0 = 0.f, a1 = 0.f;
        for (int t2 = 0; t2 < 64; t2 += 8) {
            float4 a = *(const float4*)(qr + t2);
            float4 w = *(const float4*)(wr + t2);
            float4 c = *(const float4*)(qr + t2 + 4);
            float4 u = *(const float4*)(wr + t2 + 4);
            a0 += a.x * w.x + a.y * w.y + a.z * w.z + a.w * w.w;
            a1 += c.x * u.x + c.y * u.y + c.z * u.z + c.w * u.w;
        }
        g_qf[i] = __float2bfloat16(a0 + a1);
    } else {                              // Wvo GEMM, batched per head (K=64)
        int wi = blk - 8704;
        int bx = wi & 3, by = (wi >> 2) & 3, h = wi >> 4;
        ACC_INIT
        long row0 = (long)bx * 128, col0 = (long)by * 128;
        gemm128(g_wob, DIM, g_wvb, DIM, row0, col0, h * 64, h * 64 + 64, As, Bs, acc);
#pragma unroll
        for (int mi = 0; mi < 4; mi++)
#pragma unroll
            for (int ni = 0; ni < 4; ni++) {
                long col = col0 + wc * 64 + ni * 16 + fr;
#pragma unroll
                for (int r = 0; r < 4; r++) {
                    long row = row0 + wr * 64 + mi * 16 + fq * 4 + r;
                    g_wvo[row * 4096 + h * 512 + col] = __float2bfloat16(acc[mi][ni][r]);
                }
            }
    }
}

// gather (unroll 8, XCD swizzle): agg[d] = bf16( dinv[d]*(xb[d] + sum xb[src]) )
__global__ __launch_bounds__(256) void k_gather() {
    int bid = blockIdx.x;
    int lb = (bid & 7) * 1024 + (bid >> 3);
    int wave = threadIdx.x >> 6, lane = threadIdx.x & 63;
    int node = lb * 4 + wave;

    bf16x8 sv = ((const bf16x8*)(g_xb + (long)node * DIM))[lane];
    float acc[8];
#pragma unroll
    for (int j = 0; j < 8; j++) acc[j] = bf2f((unsigned short)sv[j]);

    int e = g_off[node], e1 = g_off[node + 1];
    for (; e + 8 <= e1; e += 8) {
        bf16x8 r[8];
#pragma unroll
        for (int q = 0; q < 8; q++)
            r[q] = ((const bf16x8*)(g_xb + (long)g_csr[e + q] * DIM))[lane];
#pragma unroll
        for (int j = 0; j < 8; j++) {
            float s01 = bf2f((unsigned short)r[0][j]) + bf2f((unsigned short)r[1][j]);
            float s23 = bf2f((unsigned short)r[2][j]) + bf2f((unsigned short)r[3][j]);
            float s45 = bf2f((unsigned short)r[4][j]) + bf2f((unsigned short)r[5][j]);
            float s67 = bf2f((unsigned short)r[6][j]) + bf2f((unsigned short)r[7][j]);
            acc[j] += (s01 + s23) + (s45 + s67);
        }
    }
    for (; e < e1; e++) {
        bf16x8 r0 = ((const bf16x8*)(g_xb + (long)g_csr[e] * DIM))[lane];
#pragma unroll
        for (int j = 0; j < 8; j++) acc[j] += bf2f((unsigned short)r0[j]);
    }
    float dd = g_dinv[node];
    bf16x8 o;
#pragma unroll
    for (int j = 0; j < 8; j++) { bf16 t = __float2bfloat16(acc[j] * dd); o[j] = *(short*)&t; }
    ((bf16x8*)(g_agg + (long)node * DIM))[lane] = o;
}

// merged: scores (512 blk, graph-major XCD swizzle) | aggT (4096 blk)
__global__ __launch_bounds__(256) void k_aggsc() {
    __shared__ __align__(16) char smem[32768];
    int blk = blockIdx.x;
    if (blk < 512) {                      // scores: C[hs][n] = QF . agg_b^T
        bf16 (*As)[128 * 32] = (bf16(*)[128 * 32])smem;
        bf16 (*Bs)[128 * 32] = (bf16(*)[128 * 32])(smem + 16384);
        int b = blk & 63, bx = (blk >> 6) & 1, by = blk >> 7;
        ACC_INIT
        long row0 = (long)bx * 128, col0 = (long)by * 128;
        gemm128(g_qf, DIM, g_agg + (long)b * (MAXN * DIM), DIM, row0, col0, 0, DIM, As, Bs, acc);
        bf16* out = g_sc + (long)b * (256 * MAXN);
#pragma unroll
        for (int mi = 0; mi < 4; mi++)
#pragma unroll
            for (int ni = 0; ni < 4; ni++) {
                long col = col0 + wc * 64 + ni * 16 + fr;
#pragma unroll
                for (int r = 0; r < 4; r++) {
                    long row = row0 + wr * 64 + mi * 16 + fq * 4 + r;
                    out[row * MAXN + col] = __float2bfloat16(acc[mi][ni][r]);
                }
            }
    } else {                              // aggT[b][d][n] = agg[b*512+n][d]
        unsigned short (*L)[72] = (unsigned short(*)[72])smem;
        int id = blk - 512;
        int b = id >> 6, t = id & 63;
        int n0 = (t & 7) * 64, d0 = (t >> 3) * 64;
        int tid = threadIdx.x;
        const unsigned short* src = (const unsigned short*)g_agg + ((long)b * 512 + n0) * 512 + d0;
#pragma unroll
        for (int p = 0; p < 2; p++) {
            int r = (tid >> 3) + 32 * p, c = (tid & 7) * 8;
            *(int4*)&L[r][c] = *(const int4*)(src + (long)r * 512 + c);
        }
        __syncthreads();
        unsigned short* dst = (unsigned short*)g_aggT + ((long)b * 512 + d0) * 512 + n0;
#pragma unroll
        for (int p = 0; p < 2; p++) {
            int dr = (tid >> 3) + 32 * p, c0 = (tid & 7) * 8;
            unsigned short tmp[8];
#pragma unroll
            for (int j = 0; j < 8; j++) tmp[j] = L[c0 + j][dr];
            *(int4*)(dst + (long)dr * 512 + c0) = *(int4*)tmp;
        }
    }
}

// in-place row softmax on g_sc (16384 rows of 512)
__global__ __launch_bounds__(256) void k_soft() {
    int w = threadIdx.x >> 6, lane = threadIdx.x & 63;
    unsigned short* base = (unsigned short*)g_sc + ((long)blockIdx.x * 16 + w * 4) * MAXN;
#pragma unroll
    for (int r = 0; r < 4; r++) {
        unsigned short* row = base + (long)r * MAXN;
        float v[8]; float m = -1e30f;
#pragma unroll
        for (int k = 0; k < 8; k++) { v[k] = bf2f(row[lane + 64 * k]); m = fmaxf(m, v[k]); }
#pragma unroll
        for (int o = 32; o > 0; o >>= 1) m = fmaxf(m, __shfl_xor(m, o));
        float sum = 0.f;
#pragma unroll
        for (int k = 0; k < 8; k++) { v[k] = __expf(v[k] - m); sum += v[k]; }
#pragma unroll
        for (int o = 32; o > 0; o >>= 1) sum += __shfl_xor(sum, o);
        float inv = 1.0f / sum;
#pragma unroll
        for (int k = 0; k < 8; k++) {
            bf16 t = __float2bfloat16(v[k] * inv);
            row[lane + 64 * k] = *(unsigned short*)&t;
        }
    }
}

// ctxpre: per (b,dh): C[hs][d] = P_b[hs][:] . aggT_b[dh*256+d][:]  (graph-major swizzle)
__global__ __launch_bounds__(256) void k_pvg() {
    __shared__ bf16 As[2][128 * 32];
    __shared__ bf16 Bs[2][128 * 32];
    int blk = blockIdx.x;
    int b = blk & 63, bx = (blk >> 6) & 1, by = (blk >> 7) & 1, dh = blk >> 8;
    ACC_INIT
    long row0 = (long)bx * 128, col0 = (long)by * 128;
    gemm128(g_sc + (long)b * (256 * MAXN), MAXN,
            g_aggT + (long)b * (DIM * MAXN) + (long)dh * (256 * MAXN), MAXN,
            row0, col0, 0, MAXN, As, Bs, acc);
#pragma unroll
    for (int mi = 0; mi < 4; mi++)
#pragma unroll
        for (int ni = 0; ni < 4; ni++) {
            long col = col0 + wc * 64 + ni * 16 + fr;
#pragma unroll
            for (int r = 0; r < 4; r++) {
                long row = row0 + wr * 64 + mi * 16 + fq * 4 + r;   // hs
                g_cp[((long)b * NS + (row & 31)) * 4096 + (row >> 5) * 512 + dh * 256 + col] =
                    __float2bfloat16(acc[mi][ni][r]);
            }
        }
}

// attn_out partials: A=g_cp [2048][4096], Bt=g_wvo [512][4096], 4-way split-K
__global__ __launch_bounds__(256) void k_vo() {
    __shared__ bf16 As[2][128 * 32];
    __shared__ bf16 Bs[2][128 * 32];
    ACC_INIT
    int z = blockIdx.z;
    long row0 = (long)blockIdx.x * 128, col0 = (long)blockIdx.y * 128;
    gemm128(g_cp, 4096, g_wvo, 4096, row0, col0, z * 1024, z * 1024 + 1024, As, Bs, acc);
    float* out = g_part + (long)z * MP;
#pragma unroll
    for (int mi = 0; mi < 4; mi++)
#pragma unroll
        for (int ni = 0; ni < 4; ni++) {
            long col = col0 + wc * 64 + ni * 16 + fr;
#pragma unroll
            for (int r = 0; r < 4; r++) {
                long row = row0 + wr * 64 + mi * 16 + fq * 4 + r;
                out[row * DIM + col] = acc[mi][ni][r];
            }
        }
}

// FFN partials: A=g_h1b [2048][512], Bt=g_wffT [512][512], 4-way split-K
__global__ __launch_bounds__(256) void k_ffn() {
    __shared__ bf16 As[2][128 * 32];
    __shared__ bf16 Bs[2][128 * 32];
    ACC_INIT
    int z = blockIdx.z;
    long row0 = (long)blockIdx.x * 128, col0 = (long)blockIdx.y * 128;
    gemm128(g_h1b, DIM, g_wffT, DIM, row0, col0, z * 128, z * 128 + 128, As, Bs, acc);
    float* out = g_part + (long)z * MP;
#pragma unroll
    for (int mi = 0; mi < 4; mi++)
#pragma unroll
        for (int ni = 0; ni < 4; ni++) {
            long col = col0 + wc * 64 + ni * 16 + fr;
#pragma unroll
            for (int r = 0; r < 4; r++) {
                long row = row0 + wr * 64 + mi * 16 + fq * 4 + r;
                out[row * DIM + col] = acc[mi][ni][r];
            }
        }
}

// ---------------- layernorms (fused split-K reduction + bias) ----------------
__device__ inline float blockReduceSum(float v, float* red, int tid) {
#pragma unroll
    for (int o = 32; o > 0; o >>= 1) v += __shfl_xor(v, o);
    __syncthreads();
    if ((tid & 63) == 0) red[tid >> 6] = v;
    __syncthreads();
    return red[0] + red[1] + red[2] + red[3];
}

__global__ __launch_bounds__(256) void k_ln1(const float* __restrict__ seed,
                                             const float* __restrict__ gamma,
                                             const float* __restrict__ beta) {
    __shared__ float red[4];
    int r = blockIdx.x, t = threadIdx.x;
    int s = r & 31;
    long base = (long)r * DIM;
    float v0 = seed[s * DIM + t] + g_bvo[t];
    float v1 = seed[s * DIM + 256 + t] + g_bvo[256 + t];
#pragma unroll
    for (int z = 0; z < 4; z++) {
        v0 += g_part[(long)z * MP + base + t];
        v1 += g_part[(long)z * MP + base + 256 + t];
    }
    float mean = blockReduceSum(v0 + v1, red, t) * (1.0f / DIM);
    float d0 = v0 - mean, d1 = v1 - mean;
    float var = blockReduceSum(d0 * d0 + d1 * d1, red, t) * (1.0f / DIM);
    float ri = rsqrtf(var + 1e-5f);
    float o0 = d0 * ri * gamma[t] + beta[t];
    float o1 = d1 * ri * gamma[256 + t] + beta[256 + t];
    g_h1[base + t] = o0; g_h1[base + 256 + t] = o1;
    g_h1b[base + t] = __float2bfloat16(o0);
    g_h1b[base + 256 + t] = __float2bfloat16(o1);
}

__global__ __launch_bounds__(256) void k_ln2(const float* __restrict__ gamma,
                                             const float* __restrict__ beta,
                                             const float* __restrict__ bff,
                                             float* __restrict__ out) {
    __shared__ float red[4];
    int r = blockIdx.x, t = threadIdx.x;
    long base = (long)r * DIM;
    float v0 = g_h1[base + t] + bff[t];
    float v1 = g_h1[base + 256 + t] + bff[256 + t];
#pragma unroll
    for (int z = 0; z < 4; z++) {
        v0 += g_part[(long)z * MP + base + t];
        v1 += g_part[(long)z * MP + base + 256 + t];
    }
    float mean = blockReduceSum(v0 + v1, red, t) * (1.0f / DIM);
    float d0 = v0 - mean, d1 = v1 - mean;
    float var = blockReduceSum(d0 * d0 + d1 * d1, red, t) * (1.0f / DIM);
    float ri = rsqrtf(var + 1e-5f);
    out[base + t] = d0 * ri * gamma[t] + beta[t];
    out[base + 256 + t] = d1 * ri * gamma[256 + t] + beta[256 + t];
}

// ---------------- launch ----------------
extern "C" void kernel_launch(void* const* d_in, const int* in_sizes, int n_in,
                              void* d_out, int out_size, void* d_ws, size_t ws_size,
                              hipStream_t stream) {
    (void)in_sizes; (void)n_in; (void)out_size; (void)d_ws; (void)ws_size;
    const float* x    = (const float*)d_in[1];
    const int*   ei   = (const int*)d_in[2];
    const int*   esrc = ei;
    const int*   edst = ei + NE;
    const float* seed = (const float*)d_in[4];
    const float* Wk   = (const float*)d_in[5];
    const float* Wv   = (const float*)d_in[7];
    const float* bv   = (const float*)d_in[8];
    const float* Wq   = (const float*)d_in[9];
    const float* Wo   = (const float*)d_in[10];
    const float* bo   = (const float*)d_in[11];
    const float* Wff  = (const float*)d_in[12];
    const float* bff  = (const float*)d_in[13];
    const float* gh   = (const float*)d_in[14];
    const float* bh   = (const float*)d_in[15];
    const float* gz   = (const float*)d_in[16];
    const float* bz   = (const float*)d_in[17];
    float* out = (float*)d_out;

    k_hist    <<<NBLK, 1024, 0, stream>>>(edst);
    k_colscan <<<NN / 512, 256, 0, stream>>>();
    k_scan    <<<1, 1024, 0, stream>>>();
    k_prep    <<<450, 256, 0, stream>>>(seed, Wq, Wo, Wv, Wff, bo, bv);
    k_fillsort<<<NBLK, 1024, 0, stream>>>(esrc, edst);
    k_xbqf    <<<8832, 256, 0, stream>>>(x, Wk);
    k_gather  <<<NN / 4, 256, 0, stream>>>();
    k_aggsc   <<<512 + BN * 64, 256, 0, stream>>>();
    k_soft    <<<1024, 256, 0, stream>>>();
    k_pvg     <<<512, 256, 0, stream>>>();
    k_vo      <<<dim3(16, 4, 4), 256, 0, stream>>>();
    k_ln1     <<<BN * NS, 256, 0, stream>>>(seed, gh, bh);
    k_ffn     <<<dim3(16, 4, 4), 256, 0, stream>>>();
    k_ln2     <<<BN * NS, 256, 0, stream>>>(gz, bz, bff, out);
}

// Round 16
// 220.941 us; speedup vs baseline: 1.4201x; 1.0013x over previous
//
#include <hip/hip_runtime.h>
#include <hip/hip_bf16.h>

#define BN   64
#define MAXN 512
#define DIM  512
#define NH   8
#define NS   32
#define NN   32768      // BN*MAXN
#define NE   524288
#define NBLK 256            // histogram blocks
#define EPB  (NE / NBLK)    // 2048 edges per block
#define MP   (2048 * 512)   // one partial slice

typedef __hip_bfloat16 bf16;
using bf16x8 = __attribute__((ext_vector_type(8))) short;   // 8 bf16 (4 VGPRs)
using f32x4  = __attribute__((ext_vector_type(4))) float;

// ---- persistent device scratch ----
__device__ int            g_cnt[NN];
__device__ int            g_off[NN + 1];
__device__ int            g_csr[NE];
__device__ unsigned short g_hist[(long)NBLK * NN];   // 16 MB
__device__ unsigned short g_bpfx[(long)NBLK * NN];   // 16 MB
__device__ float g_dinv[NN];
__device__ bf16  g_xb[NN * DIM];             // 32 MB
__device__ bf16  g_agg[NN * DIM];            // 32 MB
__device__ bf16  g_aggT[NN * DIM];           // 32 MB [b][d][n]
__device__ bf16  g_qf[256 * DIM];            // QF[h*32+s][d]
__device__ bf16  g_wob[DIM * DIM];           // Wo bf16
__device__ bf16  g_wvb[DIM * DIM];           // Wv bf16
__device__ bf16  g_wvo[DIM * 8 * DIM];       // 4 MB [e][h*512+d]
__device__ float g_bvo[DIM];
__device__ bf16  g_wffT[DIM * DIM];
__device__ float g_q[NS * DIM];
__device__ bf16  g_sc[BN * 256 * MAXN];      // scores -> P (in-place softmax)
__device__ bf16  g_cp[BN * NS * 8 * DIM];    // ctxpre [b*32+s][h*512+d]
__device__ float g_part[4 * MP];             // split-K partials
__device__ float g_h1[BN * NS * DIM];
__device__ bf16  g_h1b[BN * NS * DIM];

__device__ inline float bf2f(unsigned short u) {
    union { unsigned int i; float f; } x; x.i = ((unsigned int)u) << 16; return x.f;
}

__device__ inline void gll16(const bf16* g, bf16* l) {
    __builtin_amdgcn_global_load_lds(
        (const __attribute__((address_space(1))) void*)g,
        (__attribute__((address_space(3))) void*)l, 16, 0, 0);
}

// ---------------- atomic-free CSR build ----------------
// stage 1: per-block LDS histogram of dst (1024 thr: 16 waves/CU hides LDS latency)
__global__ __launch_bounds__(1024) void k_hist(const int* __restrict__ dst) {
    __shared__ unsigned int h[NN];               // 128 KB
    int p = blockIdx.x, tid = threadIdx.x;
    for (int i = tid; i < NN / 4; i += 1024) ((int4*)h)[i] = make_int4(0, 0, 0, 0);
    __syncthreads();
#pragma unroll
    for (int j = 0; j < EPB / 1024; j++) {
        int e = p * EPB + j * 1024 + tid;
        atomicAdd(&h[dst[e]], 1u);
    }
    __syncthreads();
    unsigned int* out32 = (unsigned int*)(g_hist + (long)p * NN);
    for (int i = tid; i < NN / 2; i += 1024)
        out32[i] = h[2 * i] | (h[2 * i + 1] << 16);
}

// stage 2: per-node-pair prefix across blocks -> bpfx (packed), totals -> cnt, dinv
__global__ __launch_bounds__(256) void k_colscan() {
    int v2 = blockIdx.x * 256 + threadIdx.x;     // bin pair (2*v2, 2*v2+1); grid 64
    const unsigned int* H = (const unsigned int*)g_hist;
    unsigned int* B = (unsigned int*)g_bpfx;
    unsigned int s0 = 0, s1 = 0;
#pragma unroll 8
    for (int p = 0; p < NBLK; p++) {
        unsigned int hh = H[(long)p * (NN / 2) + v2];
        B[(long)p * (NN / 2) + v2] = s0 | (s1 << 16);
        s0 += hh & 0xffffu; s1 += hh >> 16;
    }
    g_cnt[2 * v2] = (int)s0;
    g_cnt[2 * v2 + 1] = (int)s1;
    g_dinv[2 * v2] = rsqrtf(1.0f + (float)s0);
    g_dinv[2 * v2 + 1] = rsqrtf(1.0f + (float)s1);
}

// stage 3: exclusive scan of counts -> offsets
__global__ void k_scan() {
    __shared__ int part[1024];
    int t = threadIdx.x;
    int base = t * 32;
    int loc[32]; int s = 0;
#pragma unroll
    for (int i = 0; i < 32; i++) { loc[i] = g_cnt[base + i]; s += loc[i]; }
    part[t] = s; __syncthreads();
    for (int o = 1; o < 1024; o <<= 1) {
        int v = (t >= o) ? part[t - o] : 0;
        __syncthreads();
        part[t] += v;
        __syncthreads();
    }
    int ex = (t == 0) ? 0 : part[t - 1];
#pragma unroll
    for (int i = 0; i < 32; i++) { g_off[base + i] = ex; ex += loc[i]; }
    if (t == 1023) g_off[NN] = ex;
}

// stage 4: deterministic placement via LDS rank counters (1024 thr, packed init)
__global__ __launch_bounds__(1024) void k_fillsort(const int* __restrict__ src,
                                                   const int* __restrict__ dst) {
    __shared__ unsigned int l[NN];               // 128 KB
    int p = blockIdx.x, tid = threadIdx.x;
    const unsigned int* bp32 = (const unsigned int*)(g_bpfx + (long)p * NN);
    for (int i = tid; i < NN / 2; i += 1024) {
        unsigned int v = bp32[i];
        ((uint2*)l)[i] = make_uint2(v & 0xffffu, v >> 16);
    }
    __syncthreads();
#pragma unroll
    for (int j = 0; j < EPB / 1024; j++) {
        int e = p * EPB + j * 1024 + tid;
        int v = dst[e];
        unsigned int r = atomicAdd(&l[v], 1u);
        g_csr[g_off[v] + r] = src[e];
    }
}

// ---------------- prep: qproj (64 blk) | weight cvt (384) | bvo (2) ----------------
__global__ __launch_bounds__(256) void k_prep(const float* __restrict__ seed,
                                              const float* __restrict__ Wq,
                                              const float* __restrict__ Wo,
                                              const float* __restrict__ Wv,
                                              const float* __restrict__ Wff,
                                              const float* __restrict__ bo,
                                              const float* __restrict__ bv) {
    int blk = blockIdx.x;
    if (blk < 64) {                       // q[s][e] = seed[s].Wq[e] / 8
        int i = blk * 256 + threadIdx.x;
        int s = i >> 9, e = i & 511;
        const float* sr = seed + s * DIM;
        const float* wr = Wq + e * DIM;
        float a0 = 0.f, a1 = 0.f;
        for (int d = 0; d < DIM; d += 8) {
            float4 a = *(const float4*)(sr + d);
            float4 b = *(const float4*)(wr + d);
            float4 c = *(const float4*)(sr + d + 4);
            float4 w = *(const float4*)(wr + d + 4);
            a0 += a.x * b.x + a.y * b.y + a.z * b.z + a.w * b.w;
            a1 += c.x * w.x + c.y * w.y + c.z * w.z + c.w * w.w;
        }
        g_q[i] = (a0 + a1) * 0.125f;
    } else if (blk < 448) {               // f32 -> bf16 weight convert
        long t = (long)(blk - 64) * 256 + threadIdx.x;
        const float* srcp; bf16* dstp; long off;
        if (t < 32768)      { srcp = Wo;  dstp = g_wob;  off = t; }
        else if (t < 65536) { srcp = Wv;  dstp = g_wvb;  off = t - 32768; }
        else                { srcp = Wff; dstp = g_wffT; off = t - 65536; }
        long i = off * 8;
        float4 a = *(const float4*)(srcp + i);
        float4 b = *(const float4*)(srcp + i + 4);
        float v[8] = {a.x, a.y, a.z, a.w, b.x, b.y, b.z, b.w};
        bf16x8 o;
#pragma unroll
        for (int j = 0; j < 8; j++) { bf16 q = __float2bfloat16(v[j]); o[j] = *(short*)&q; }
        *(bf16x8*)(dstp + i) = o;
    } else {                              // bvo[e] = bo[e] + bv . Wo[e]
        int e = (blk - 448) * 256 + threadIdx.x;
        const float* orow = Wo + (long)e * DIM;
        float a0 = 0.f, a1 = 0.f;
        for (int c = 0; c < DIM; c += 8) {
            float4 a = *(const float4*)(bv + c);
            float4 w = *(const float4*)(orow + c);
            float4 xx = *(const float4*)(bv + c + 4);
            float4 u = *(const float4*)(orow + c + 4);
            a0 += a.x * w.x + a.y * w.y + a.z * w.z + a.w * w.w;
            a1 += xx.x * u.x + xx.y * u.y + xx.z * u.z + xx.w * u.w;
        }
        g_bvo[e] = bo[e] + a0 + a1;
    }
}

// ---------------- shared 128x128 MFMA GEMM core (swizzled gll + dbuf) ----------------
__device__ __forceinline__ void gemm128(const bf16* __restrict__ A, long lda,
                                        const bf16* __restrict__ Bt, long ldb,
                                        long row0, long col0, int kbeg, int kend,
                                        bf16 (*As)[128 * 32], bf16 (*Bs)[128 * 32],
                                        f32x4 acc[4][4]) {
    int tid = threadIdx.x;
    int lane = tid & 63, wave = tid >> 6;
    int wr = wave >> 1, wc = wave & 1;
    int fr = lane & 15, fq = lane >> 4;
    int rchunk = (fq ^ ((fr >> 1) & 3)) * 8;
    int u0 = wave * 128 + lane;
    int sr0 = u0 >> 2, sc0 = ((u0 & 3) ^ ((sr0 >> 1) & 3)) * 8;
    int u1 = u0 + 64;
    int sr1 = u1 >> 2, sc1 = ((u1 & 3) ^ ((sr1 >> 1) & 3)) * 8;

    auto stage = [&](int buf, int kt) {
        gll16(A + (row0 + sr0) * lda + kt + sc0, As[buf] + u0 * 8);
        gll16(A + (row0 + sr1) * lda + kt + sc1, As[buf] + u1 * 8);
        gll16(Bt + (col0 + sr0) * ldb + kt + sc0, Bs[buf] + u0 * 8);
        gll16(Bt + (col0 + sr1) * ldb + kt + sc1, Bs[buf] + u1 * 8);
    };

    stage(0, kbeg);
    __syncthreads();
    for (int kt = kbeg; kt < kend; kt += 32) {
        int buf = ((kt - kbeg) >> 5) & 1;
        if (kt + 32 < kend) stage(buf ^ 1, kt + 32);
        bf16x8 af[4], bfv[4];
#pragma unroll
        for (int mi = 0; mi < 4; mi++)
            af[mi] = *(const bf16x8*)(As[buf] + (wr * 64 + mi * 16 + fr) * 32 + rchunk);
#pragma unroll
        for (int ni = 0; ni < 4; ni++)
            bfv[ni] = *(const bf16x8*)(Bs[buf] + (wc * 64 + ni * 16 + fr) * 32 + rchunk);
#pragma unroll
        for (int mi = 0; mi < 4; mi++)
#pragma unroll
            for (int ni = 0; ni < 4; ni++)
                acc[mi][ni] = __builtin_amdgcn_mfma_f32_16x16x32_bf16(af[mi], bfv[ni], acc[mi][ni], 0, 0, 0);
        __syncthreads();
    }
}

#define ACC_INIT                                             \
    f32x4 acc[4][4];                                         \
    _Pragma("unroll")                                        \
    for (int i = 0; i < 4; i++)                              \
        _Pragma("unroll")                                    \
        for (int j = 0; j < 4; j++) acc[i][j] = (f32x4){0.f, 0.f, 0.f, 0.f}; \
    int lane = threadIdx.x & 63, wave = threadIdx.x >> 6;    \
    int wr = wave >> 1, wc = wave & 1;                       \
    int fr = lane & 15, fq = lane >> 4;

// merged: xb (8192 blk) | qf (512) | wvo (128)
__global__ __launch_bounds__(256) void k_xbqf(const float* __restrict__ x,
                                              const float* __restrict__ Wk) {
    __shared__ bf16 As[2][128 * 32];
    __shared__ bf16 Bs[2][128 * 32];
    int blk = blockIdx.x;
    if (blk < 8192) {                     // xb = bf16(x * dinv)
        long i = (long)blk * (256 * 8) + (long)threadIdx.x * 8;
        int node = (int)(i >> 9);
        float w = g_dinv[node];
        float4 a = *(const float4*)(x + i);
        float4 b = *(const float4*)(x + i + 4);
        float v[8] = {a.x, a.y, a.z, a.w, b.x, b.y, b.z, b.w};
        bf16x8 o;
#pragma unroll
        for (int j = 0; j < 8; j++) { bf16 t = __float2bfloat16(v[j] * w); o[j] = *(short*)&t; }
        *(bf16x8*)(g_xb + i) = o;
    } else if (blk < 8704) {              // QF[hs][d]
        int i = (blk - 8192) * 256 + threadIdx.x;
        int hs = i >> 9, d = i & 511;
        int h = hs >> 5, s = hs & 31;
        const float* qr = g_q + s * DIM + h * 64;
        const float* wr = Wk + d * DIM + h * 64;
        float a0 = 0.f, a1 = 0.f;
        for (int t2 = 0; t2 < 64; t2 += 8) {
            float4 a = *(const float4*)(qr + t2);
            float4 w = *(const float4*)(wr + t2);
            float4 c = *(const float4*)(qr + t2 + 4);
            float4 u = *(const float4*)(wr + t2 + 4);
            a0 += a.x * w.x + a.y * w.y + a.z * w.z + a.w * w.w;
            a1 += c.x * u.x + c.y * u.y + c.z * u.z + c.w * u.w;
        }
        g_qf[i] = __float2bfloat16(a0 + a1);
    } else {                              // Wvo GEMM, batched per head (K=64)
        int wi = blk - 8704;
        int bx = wi & 3, by = (wi >> 2) & 3, h = wi >> 4;
        ACC_INIT
        long row0 = (long)bx * 128, col0 = (long)by * 128;
        gemm128(g_wob, DIM, g_wvb, DIM, row0, col0, h * 64, h * 64 + 64, As, Bs, acc);
#pragma unroll
        for (int mi = 0; mi < 4; mi++)
#pragma unroll
            for (int ni = 0; ni < 4; ni++) {
                long col = col0 + wc * 64 + ni * 16 + fr;
#pragma unroll
                for (int r = 0; r < 4; r++) {
                    long row = row0 + wr * 64 + mi * 16 + fq * 4 + r;
                    g_wvo[row * 4096 + h * 512 + col] = __float2bfloat16(acc[mi][ni][r]);
                }
            }
    }
}

// ---------------- gather + fused transpose ----------------
// 16 waves, 32 consecutive nodes per block (wave w handles nodes 2w, 2w+1).
// Per-node edge walk identical to the measured k_gather; outputs agg (coalesced)
// and aggT tiles via pad-33 LDS (saves the separate 67MB transpose round-trip).
__global__ __launch_bounds__(1024) void k_gather3() {
    __shared__ unsigned short T[512 * 33];       // 33.8 KB
    int bid = blockIdx.x;                        // 1024 blocks
    int gb = (bid & 7) * 128 + (bid >> 3);       // XCD swizzle: 8 graphs per XCD
    int b = gb >> 4, nt = gb & 15;
    int w = threadIdx.x >> 6, lane = threadIdx.x & 63;

#pragma unroll
    for (int k = 0; k < 2; k++) {
        int nl = w * 2 + k;                      // local node 0..31
        int node = b * 512 + nt * 32 + nl;

        bf16x8 sv = ((const bf16x8*)(g_xb + (long)node * DIM))[lane];
        float acc[8];
#pragma unroll
        for (int j = 0; j < 8; j++) acc[j] = bf2f((unsigned short)sv[j]);

        int e = g_off[node], e1 = g_off[node + 1];
        for (; e + 8 <= e1; e += 8) {
            bf16x8 r[8];
#pragma unroll
            for (int q = 0; q < 8; q++)
                r[q] = ((const bf16x8*)(g_xb + (long)g_csr[e + q] * DIM))[lane];
#pragma unroll
            for (int j = 0; j < 8; j++) {
                float s01 = bf2f((unsigned short)r[0][j]) + bf2f((unsigned short)r[1][j]);
                float s23 = bf2f((unsigned short)r[2][j]) + bf2f((unsigned short)r[3][j]);
                float s45 = bf2f((unsigned short)r[4][j]) + bf2f((unsigned short)r[5][j]);
                float s67 = bf2f((unsigned short)r[6][j]) + bf2f((unsigned short)r[7][j]);
                acc[j] += (s01 + s23) + (s45 + s67);
            }
        }
        for (; e < e1; e++) {
            bf16x8 r0 = ((const bf16x8*)(g_xb + (long)g_csr[e] * DIM))[lane];
#pragma unroll
            for (int j = 0; j < 8; j++) acc[j] += bf2f((unsigned short)r0[j]);
        }
        float dd = g_dinv[node];
        bf16x8 o;
#pragma unroll
        for (int j = 0; j < 8; j++) {
            bf16 t = __float2bfloat16(acc[j] * dd);
            o[j] = *(short*)&t;
            T[(lane * 8 + j) * 33 + nl] = *(unsigned short*)&t;
        }
        ((bf16x8*)(g_agg + (long)node * DIM))[lane] = o;
    }
    __syncthreads();

    // transposed write: thread t -> feature f = t>>1, half = t&1 (16 n-values, 32B)
    int f = threadIdx.x >> 1, half = threadIdx.x & 1;
    unsigned short tmp[16];
#pragma unroll
    for (int j = 0; j < 16; j++) tmp[j] = T[f * 33 + half * 16 + j];
    unsigned short* dst = (unsigned short*)g_aggT + ((long)b * 512 + f) * 512 + nt * 32 + half * 16;
    *(int4*)dst = *(int4*)tmp;
    *(int4*)(dst + 8) = *(int4*)(tmp + 8);
}

// scores (512 blk, graph-major XCD swizzle): C[hs][n] = QF . agg_b^T
__global__ __launch_bounds__(256) void k_score() {
    __shared__ bf16 As[2][128 * 32];
    __shared__ bf16 Bs[2][128 * 32];
    int blk = blockIdx.x;
    int b = blk & 63, bx = (blk >> 6) & 1, by = blk >> 7;
    ACC_INIT
    long row0 = (long)bx * 128, col0 = (long)by * 128;
    gemm128(g_qf, DIM, g_agg + (long)b * (MAXN * DIM), DIM, row0, col0, 0, DIM, As, Bs, acc);
    bf16* out = g_sc + (long)b * (256 * MAXN);
#pragma unroll
    for (int mi = 0; mi < 4; mi++)
#pragma unroll
        for (int ni = 0; ni < 4; ni++) {
            long col = col0 + wc * 64 + ni * 16 + fr;
#pragma unroll
            for (int r = 0; r < 4; r++) {
                long row = row0 + wr * 64 + mi * 16 + fq * 4 + r;
                out[row * MAXN + col] = __float2bfloat16(acc[mi][ni][r]);
            }
        }
}

// in-place row softmax on g_sc (16384 rows of 512)
__global__ __launch_bounds__(256) void k_soft() {
    int w = threadIdx.x >> 6, lane = threadIdx.x & 63;
    unsigned short* base = (unsigned short*)g_sc + ((long)blockIdx.x * 16 + w * 4) * MAXN;
#pragma unroll
    for (int r = 0; r < 4; r++) {
        unsigned short* row = base + (long)r * MAXN;
        float v[8]; float m = -1e30f;
#pragma unroll
        for (int k = 0; k < 8; k++) { v[k] = bf2f(row[lane + 64 * k]); m = fmaxf(m, v[k]); }
#pragma unroll
        for (int o = 32; o > 0; o >>= 1) m = fmaxf(m, __shfl_xor(m, o));
        float sum = 0.f;
#pragma unroll
        for (int k = 0; k < 8; k++) { v[k] = __expf(v[k] - m); sum += v[k]; }
#pragma unroll
        for (int o = 32; o > 0; o >>= 1) sum += __shfl_xor(sum, o);
        float inv = 1.0f / sum;
#pragma unroll
        for (int k = 0; k < 8; k++) {
            bf16 t = __float2bfloat16(v[k] * inv);
            row[lane + 64 * k] = *(unsigned short*)&t;
        }
    }
}

// ctxpre: per (b,dh): C[hs][d] = P_b[hs][:] . aggT_b[dh*256+d][:]  (graph-major swizzle)
__global__ __launch_bounds__(256) void k_pvg() {
    __shared__ bf16 As[2][128 * 32];
    __shared__ bf16 Bs[2][128 * 32];
    int blk = blockIdx.x;
    int b = blk & 63, bx = (blk >> 6) & 1, by = (blk >> 7) & 1, dh = blk >> 8;
    ACC_INIT
    long row0 = (long)bx * 128, col0 = (long)by * 128;
    gemm128(g_sc + (long)b * (256 * MAXN), MAXN,
            g_aggT + (long)b * (DIM * MAXN) + (long)dh * (256 * MAXN), MAXN,
            row0, col0, 0, MAXN, As, Bs, acc);
#pragma unroll
    for (int mi = 0; mi < 4; mi++)
#pragma unroll
        for (int ni = 0; ni < 4; ni++) {
            long col = col0 + wc * 64 + ni * 16 + fr;
#pragma unroll
            for (int r = 0; r < 4; r++) {
                long row = row0 + wr * 64 + mi * 16 + fq * 4 + r;   // hs
                g_cp[((long)b * NS + (row & 31)) * 4096 + (row >> 5) * 512 + dh * 256 + col] =
                    __float2bfloat16(acc[mi][ni][r]);
            }
        }
}

// attn_out partials: A=g_cp [2048][4096], Bt=g_wvo [512][4096], 4-way split-K
__global__ __launch_bounds__(256) void k_vo() {
    __shared__ bf16 As[2][128 * 32];
    __shared__ bf16 Bs[2][128 * 32];
    ACC_INIT
    int z = blockIdx.z;
    long row0 = (long)blockIdx.x * 128, col0 = (long)blockIdx.y * 128;
    gemm128(g_cp, 4096, g_wvo, 4096, row0, col0, z * 1024, z * 1024 + 1024, As, Bs, acc);
    float* out = g_part + (long)z * MP;
#pragma unroll
    for (int mi = 0; mi < 4; mi++)
#pragma unroll
        for (int ni = 0; ni < 4; ni++) {
            long col = col0 + wc * 64 + ni * 16 + fr;
#pragma unroll
            for (int r = 0; r < 4; r++) {
                long row = row0 + wr * 64 + mi * 16 + fq * 4 + r;
                out[row * DIM + col] = acc[mi][ni][r];
            }
        }
}

// FFN partials: A=g_h1b [2048][512], Bt=g_wffT [512][512], 4-way split-K
__global__ __launch_bounds__(256) void k_ffn() {
    __shared__ bf16 As[2][128 * 32];
    __shared__ bf16 Bs[2][128 * 32];
    ACC_INIT
    int z = blockIdx.z;
    long row0 = (long)blockIdx.x * 128, col0 = (long)blockIdx.y * 128;
    gemm128(g_h1b, DIM, g_wffT, DIM, row0, col0, z * 128, z * 128 + 128, As, Bs, acc);
    float* out = g_part + (long)z * MP;
#pragma unroll
    for (int mi = 0; mi < 4; mi++)
#pragma unroll
        for (int ni = 0; ni < 4; ni++) {
            long col = col0 + wc * 64 + ni * 16 + fr;
#pragma unroll
            for (int r = 0; r < 4; r++) {
                long row = row0 + wr * 64 + mi * 16 + fq * 4 + r;
                out[row * DIM + col] = acc[mi][ni][r];
            }
        }
}

// ---------------- layernorms (fused split-K reduction + bias) ----------------
__device__ inline float blockReduceSum(float v, float* red, int tid) {
#pragma unroll
    for (int o = 32; o > 0; o >>= 1) v += __shfl_xor(v, o);
    __syncthreads();
    if ((tid & 63) == 0) red[tid >> 6] = v;
    __syncthreads();
    return red[0] + red[1] + red[2] + red[3];
}

__global__ __launch_bounds__(256) void k_ln1(const float* __restrict__ seed,
                                             const float* __restrict__ gamma,
                                             const float* __restrict__ beta) {
    __shared__ float red[4];
    int r = blockIdx.x, t = threadIdx.x;
    int s = r & 31;
    long base = (long)r * DIM;
    float v0 = seed[s * DIM + t] + g_bvo[t];
    float v1 = seed[s * DIM + 256 + t] + g_bvo[256 + t];
#pragma unroll
    for (int z = 0; z < 4; z++) {
        v0 += g_part[(long)z * MP + base + t];
        v1 += g_part[(long)z * MP + base + 256 + t];
    }
    float mean = blockReduceSum(v0 + v1, red, t) * (1.0f / DIM);
    float d0 = v0 - mean, d1 = v1 - mean;
    float var = blockReduceSum(d0 * d0 + d1 * d1, red, t) * (1.0f / DIM);
    float ri = rsqrtf(var + 1e-5f);
    float o0 = d0 * ri * gamma[t] + beta[t];
    float o1 = d1 * ri * gamma[256 + t] + beta[256 + t];
    g_h1[base + t] = o0; g_h1[base + 256 + t] = o1;
    g_h1b[base + t] = __float2bfloat16(o0);
    g_h1b[base + 256 + t] = __float2bfloat16(o1);
}

__global__ __launch_bounds__(256) void k_ln2(const float* __restrict__ gamma,
                                             const float* __restrict__ beta,
                                             const float* __restrict__ bff,
                                             float* __restrict__ out) {
    __shared__ float red[4];
    int r = blockIdx.x, t = threadIdx.x;
    long base = (long)r * DIM;
    float v0 = g_h1[base + t] + bff[t];
    float v1 = g_h1[base + 256 + t] + bff[256 + t];
#pragma unroll
    for (int z = 0; z < 4; z++) {
        v0 += g_part[(long)z * MP + base + t];
        v1 += g_part[(long)z * MP + base + 256 + t];
    }
    float mean = blockReduceSum(v0 + v1, red, t) * (1.0f / DIM);
    float d0 = v0 - mean, d1 = v1 - mean;
    float var = blockReduceSum(d0 * d0 + d1 * d1, red, t) * (1.0f / DIM);
    float ri = rsqrtf(var + 1e-5f);
    out[base + t] = d0 * ri * gamma[t] + beta[t];
    out[base + 256 + t] = d1 * ri * gamma[256 + t] + beta[256 + t];
}

// ---------------- launch ----------------
extern "C" void kernel_launch(void* const* d_in, const int* in_sizes, int n_in,
                              void* d_out, int out_size, void* d_ws, size_t ws_size,
                              hipStream_t stream) {
    (void)in_sizes; (void)n_in; (void)out_size; (void)d_ws; (void)ws_size;
    const float* x    = (const float*)d_in[1];
    const int*   ei   = (const int*)d_in[2];
    const int*   esrc = ei;
    const int*   edst = ei + NE;
    const float* seed = (const float*)d_in[4];
    const float* Wk   = (const float*)d_in[5];
    const float* Wv   = (const float*)d_in[7];
    const float* bv   = (const float*)d_in[8];
    const float* Wq   = (const float*)d_in[9];
    const float* Wo   = (const float*)d_in[10];
    const float* bo   = (const float*)d_in[11];
    const float* Wff  = (const float*)d_in[12];
    const float* bff  = (const float*)d_in[13];
    const float* gh   = (const float*)d_in[14];
    const float* bh   = (const float*)d_in[15];
    const float* gz   = (const float*)d_in[16];
    const float* bz   = (const float*)d_in[17];
    float* out = (float*)d_out;

    k_hist    <<<NBLK, 1024, 0, stream>>>(edst);
    k_colscan <<<NN / 512, 256, 0, stream>>>();
    k_scan    <<<1, 1024, 0, stream>>>();
    k_prep    <<<450, 256, 0, stream>>>(seed, Wq, Wo, Wv, Wff, bo, bv);
    k_fillsort<<<NBLK, 1024, 0, stream>>>(esrc, edst);
    k_xbqf    <<<8832, 256, 0, stream>>>(x, Wk);
    k_gather3 <<<1024, 1024, 0, stream>>>();
    k_score   <<<512, 256, 0, stream>>>();
    k_soft    <<<1024, 256, 0, stream>>>();
    k_pvg     <<<512, 256, 0, stream>>>();
    k_vo      <<<dim3(16, 4, 4), 256, 0, stream>>>();
    k_ln1     <<<BN * NS, 256, 0, stream>>>(seed, gh, bh);
    k_ffn     <<<dim3(16, 4, 4), 256, 0, stream>>>();
    k_ln2     <<<BN * NS, 256, 0, stream>>>(gz, bz, bff, out);
}

// Round 17
// 220.180 us; speedup vs baseline: 1.4250x; 1.0035x over previous
//
#include <hip/hip_runtime.h>
#include <hip/hip_bf16.h>

#define BN   64
#define MAXN 512
#define DIM  512
#define NH   8
#define NS   32
#define NN   32768      // BN*MAXN
#define NE   524288
#define NBLK 256            // histogram blocks
#define EPB  (NE / NBLK)    // 2048 edges per block
#define MP   (2048 * 512)   // one partial slice

typedef __hip_bfloat16 bf16;
using bf16x8 = __attribute__((ext_vector_type(8))) short;   // 8 bf16 (4 VGPRs)
using f32x4  = __attribute__((ext_vector_type(4))) float;

// ---- persistent device scratch ----
__device__ int            g_cnt[NN];
__device__ int            g_off[NN + 1];
__device__ int            g_csr[NE];
__device__ unsigned short g_hist[(long)NBLK * NN];   // 16 MB
__device__ unsigned short g_bpfx[(long)NBLK * NN];   // 16 MB
__device__ float g_dinv[NN];
__device__ bf16  g_xb[NN * DIM];             // 32 MB
__device__ bf16  g_agg[NN * DIM];            // 32 MB
__device__ bf16  g_aggT[NN * DIM];           // 32 MB [b][d][n]
__device__ bf16  g_qf[256 * DIM];            // QF[h*32+s][d]
__device__ bf16  g_wob[DIM * DIM];           // Wo bf16
__device__ bf16  g_wvb[DIM * DIM];           // Wv bf16
__device__ bf16  g_wvo[DIM * 8 * DIM];       // 4 MB [e][h*512+d]
__device__ float g_bvo[DIM];
__device__ bf16  g_wffT[DIM * DIM];
__device__ float g_q[NS * DIM];
__device__ bf16  g_sc[BN * 256 * MAXN];      // scores -> P (in-place softmax)
__device__ bf16  g_cp[BN * NS * 8 * DIM];    // ctxpre [b*32+s][h*512+d]
__device__ float g_part[4 * MP];             // split-K partials
__device__ float g_h1[BN * NS * DIM];
__device__ bf16  g_h1b[BN * NS * DIM];

__device__ inline float bf2f(unsigned short u) {
    union { unsigned int i; float f; } x; x.i = ((unsigned int)u) << 16; return x.f;
}

__device__ inline void gll16(const bf16* g, bf16* l) {
    __builtin_amdgcn_global_load_lds(
        (const __attribute__((address_space(1))) void*)g,
        (__attribute__((address_space(3))) void*)l, 16, 0, 0);
}

// ---------------- atomic-free CSR build ----------------
// stage 1: per-block LDS histogram of dst (1024 thr: 16 waves/CU hides LDS latency)
__global__ __launch_bounds__(1024) void k_hist(const int* __restrict__ dst) {
    __shared__ unsigned int h[NN];               // 128 KB
    int p = blockIdx.x, tid = threadIdx.x;
    for (int i = tid; i < NN / 4; i += 1024) ((int4*)h)[i] = make_int4(0, 0, 0, 0);
    __syncthreads();
#pragma unroll
    for (int j = 0; j < EPB / 1024; j++) {
        int e = p * EPB + j * 1024 + tid;
        atomicAdd(&h[dst[e]], 1u);
    }
    __syncthreads();
    unsigned int* out32 = (unsigned int*)(g_hist + (long)p * NN);
    for (int i = tid; i < NN / 2; i += 1024)
        out32[i] = h[2 * i] | (h[2 * i + 1] << 16);
}

// stage 2: per-node-pair prefix across blocks -> bpfx (packed), totals -> cnt, dinv
__global__ __launch_bounds__(256) void k_colscan() {
    int v2 = blockIdx.x * 256 + threadIdx.x;     // bin pair (2*v2, 2*v2+1); grid 64
    const unsigned int* H = (const unsigned int*)g_hist;
    unsigned int* B = (unsigned int*)g_bpfx;
    unsigned int s0 = 0, s1 = 0;
#pragma unroll 8
    for (int p = 0; p < NBLK; p++) {
        unsigned int hh = H[(long)p * (NN / 2) + v2];
        B[(long)p * (NN / 2) + v2] = s0 | (s1 << 16);
        s0 += hh & 0xffffu; s1 += hh >> 16;
    }
    g_cnt[2 * v2] = (int)s0;
    g_cnt[2 * v2 + 1] = (int)s1;
    g_dinv[2 * v2] = rsqrtf(1.0f + (float)s0);
    g_dinv[2 * v2 + 1] = rsqrtf(1.0f + (float)s1);
}

// stage 3: exclusive scan of counts -> offsets
__global__ void k_scan() {
    __shared__ int part[1024];
    int t = threadIdx.x;
    int base = t * 32;
    int loc[32]; int s = 0;
#pragma unroll
    for (int i = 0; i < 32; i++) { loc[i] = g_cnt[base + i]; s += loc[i]; }
    part[t] = s; __syncthreads();
    for (int o = 1; o < 1024; o <<= 1) {
        int v = (t >= o) ? part[t - o] : 0;
        __syncthreads();
        part[t] += v;
        __syncthreads();
    }
    int ex = (t == 0) ? 0 : part[t - 1];
#pragma unroll
    for (int i = 0; i < 32; i++) { g_off[base + i] = ex; ex += loc[i]; }
    if (t == 1023) g_off[NN] = ex;
}

// stage 4: deterministic placement via LDS rank counters (1024 thr, packed init)
__global__ __launch_bounds__(1024) void k_fillsort(const int* __restrict__ src,
                                                   const int* __restrict__ dst) {
    __shared__ unsigned int l[NN];               // 128 KB
    int p = blockIdx.x, tid = threadIdx.x;
    const unsigned int* bp32 = (const unsigned int*)(g_bpfx + (long)p * NN);
    for (int i = tid; i < NN / 2; i += 1024) {
        unsigned int v = bp32[i];
        ((uint2*)l)[i] = make_uint2(v & 0xffffu, v >> 16);
    }
    __syncthreads();
#pragma unroll
    for (int j = 0; j < EPB / 1024; j++) {
        int e = p * EPB + j * 1024 + tid;
        int v = dst[e];
        unsigned int r = atomicAdd(&l[v], 1u);
        g_csr[g_off[v] + r] = src[e];
    }
}

// ---------------- prep: qproj (64 blk) | weight cvt (384) | bvo (2) ----------------
__global__ __launch_bounds__(256) void k_prep(const float* __restrict__ seed,
                                              const float* __restrict__ Wq,
                                              const float* __restrict__ Wo,
                                              const float* __restrict__ Wv,
                                              const float* __restrict__ Wff,
                                              const float* __restrict__ bo,
                                              const float* __restrict__ bv) {
    int blk = blockIdx.x;
    if (blk < 64) {                       // q[s][e] = seed[s].Wq[e] / 8
        int i = blk * 256 + threadIdx.x;
        int s = i >> 9, e = i & 511;
        const float* sr = seed + s * DIM;
        const float* wr = Wq + e * DIM;
        float a0 = 0.f, a1 = 0.f;
        for (int d = 0; d < DIM; d += 8) {
            float4 a = *(const float4*)(sr + d);
            float4 b = *(const float4*)(wr + d);
            float4 c = *(const float4*)(sr + d + 4);
            float4 w = *(const float4*)(wr + d + 4);
            a0 += a.x * b.x + a.y * b.y + a.z * b.z + a.w * b.w;
            a1 += c.x * w.x + c.y * w.y + c.z * w.z + c.w * w.w;
        }
        g_q[i] = (a0 + a1) * 0.125f;
    } else if (blk < 448) {               // f32 -> bf16 weight convert
        long t = (long)(blk - 64) * 256 + threadIdx.x;
        const float* srcp; bf16* dstp; long off;
        if (t < 32768)      { srcp = Wo;  dstp = g_wob;  off = t; }
        else if (t < 65536) { srcp = Wv;  dstp = g_wvb;  off = t - 32768; }
        else                { srcp = Wff; dstp = g_wffT; off = t - 65536; }
        long i = off * 8;
        float4 a = *(const float4*)(srcp + i);
        float4 b = *(const float4*)(srcp + i + 4);
        float v[8] = {a.x, a.y, a.z, a.w, b.x, b.y, b.z, b.w};
        bf16x8 o;
#pragma unroll
        for (int j = 0; j < 8; j++) { bf16 q = __float2bfloat16(v[j]); o[j] = *(short*)&q; }
        *(bf16x8*)(dstp + i) = o;
    } else {                              // bvo[e] = bo[e] + bv . Wo[e]
        int e = (blk - 448) * 256 + threadIdx.x;
        const float* orow = Wo + (long)e * DIM;
        float a0 = 0.f, a1 = 0.f;
        for (int c = 0; c < DIM; c += 8) {
            float4 a = *(const float4*)(bv + c);
            float4 w = *(const float4*)(orow + c);
            float4 xx = *(const float4*)(bv + c + 4);
            float4 u = *(const float4*)(orow + c + 4);
            a0 += a.x * w.x + a.y * w.y + a.z * w.z + a.w * w.w;
            a1 += xx.x * u.x + xx.y * u.y + xx.z * u.z + xx.w * u.w;
        }
        g_bvo[e] = bo[e] + a0 + a1;
    }
}

// ---------------- shared 128x128 MFMA GEMM core (swizzled gll + dbuf) ----------------
__device__ __forceinline__ void gemm128(const bf16* __restrict__ A, long lda,
                                        const bf16* __restrict__ Bt, long ldb,
                                        long row0, long col0, int kbeg, int kend,
                                        bf16 (*As)[128 * 32], bf16 (*Bs)[128 * 32],
                                        f32x4 acc[4][4]) {
    int tid = threadIdx.x;
    int lane = tid & 63, wave = tid >> 6;
    int wr = wave >> 1, wc = wave & 1;
    int fr = lane & 15, fq = lane >> 4;
    int rchunk = (fq ^ ((fr >> 1) & 3)) * 8;
    int u0 = wave * 128 + lane;
    int sr0 = u0 >> 2, sc0 = ((u0 & 3) ^ ((sr0 >> 1) & 3)) * 8;
    int u1 = u0 + 64;
    int sr1 = u1 >> 2, sc1 = ((u1 & 3) ^ ((sr1 >> 1) & 3)) * 8;

    auto stage = [&](int buf, int kt) {
        gll16(A + (row0 + sr0) * lda + kt + sc0, As[buf] + u0 * 8);
        gll16(A + (row0 + sr1) * lda + kt + sc1, As[buf] + u1 * 8);
        gll16(Bt + (col0 + sr0) * ldb + kt + sc0, Bs[buf] + u0 * 8);
        gll16(Bt + (col0 + sr1) * ldb + kt + sc1, Bs[buf] + u1 * 8);
    };

    stage(0, kbeg);
    __syncthreads();
    for (int kt = kbeg; kt < kend; kt += 32) {
        int buf = ((kt - kbeg) >> 5) & 1;
        if (kt + 32 < kend) stage(buf ^ 1, kt + 32);
        bf16x8 af[4], bfv[4];
#pragma unroll
        for (int mi = 0; mi < 4; mi++)
            af[mi] = *(const bf16x8*)(As[buf] + (wr * 64 + mi * 16 + fr) * 32 + rchunk);
#pragma unroll
        for (int ni = 0; ni < 4; ni++)
            bfv[ni] = *(const bf16x8*)(Bs[buf] + (wc * 64 + ni * 16 + fr) * 32 + rchunk);
#pragma unroll
        for (int mi = 0; mi < 4; mi++)
#pragma unroll
            for (int ni = 0; ni < 4; ni++)
                acc[mi][ni] = __builtin_amdgcn_mfma_f32_16x16x32_bf16(af[mi], bfv[ni], acc[mi][ni], 0, 0, 0);
        __syncthreads();
    }
}

#define ACC_INIT                                             \
    f32x4 acc[4][4];                                         \
    _Pragma("unroll")                                        \
    for (int i = 0; i < 4; i++)                              \
        _Pragma("unroll")                                    \
        for (int j = 0; j < 4; j++) acc[i][j] = (f32x4){0.f, 0.f, 0.f, 0.f}; \
    int lane = threadIdx.x & 63, wave = threadIdx.x >> 6;    \
    int wr = wave >> 1, wc = wave & 1;                       \
    int fr = lane & 15, fq = lane >> 4;

// merged: xb (8192 blk) | qf (512) | wvo (128)
__global__ __launch_bounds__(256) void k_xbqf(const float* __restrict__ x,
                                              const float* __restrict__ Wk) {
    __shared__ bf16 As[2][128 * 32];
    __shared__ bf16 Bs[2][128 * 32];
    int blk = blockIdx.x;
    if (blk < 8192) {                     // xb = bf16(x * dinv)
        long i = (long)blk * (256 * 8) + (long)threadIdx.x * 8;
        int node = (int)(i >> 9);
        float w = g_dinv[node];
        float4 a = *(const float4*)(x + i);
        float4 b = *(const float4*)(x + i + 4);
        float v[8] = {a.x, a.y, a.z, a.w, b.x, b.y, b.z, b.w};
        bf16x8 o;
#pragma unroll
        for (int j = 0; j < 8; j++) { bf16 t = __float2bfloat16(v[j] * w); o[j] = *(short*)&t; }
        *(bf16x8*)(g_xb + i) = o;
    } else if (blk < 8704) {              // QF[hs][d]
        int i = (blk - 8192) * 256 + threadIdx.x;
        int hs = i >> 9, d = i & 511;
        int h = hs >> 5, s = hs & 31;
        const float* qr = g_q + s * DIM + h * 64;
        const float* wr = Wk + d * DIM + h * 64;
        float a0 = 0.f, a1 = 0.f;
        for (int t2 = 0; t2 < 64; t2 += 8) {
            float4 a = *(const float4*)(qr + t2);
            float4 w = *(const float4*)(wr + t2);
            float4 c = *(const float4*)(qr + t2 + 4);
            float4 u = *(const float4*)(wr + t2 + 4);
            a0 += a.x * w.x + a.y * w.y + a.z * w.z + a.w * w.w;
            a1 += c.x * u.x + c.y * u.y + c.z * u.z + c.w * u.w;
        }
        g_qf[i] = __float2bfloat16(a0 + a1);
    } else {                              // Wvo GEMM, batched per head (K=64)
        int wi = blk - 8704;
        int bx = wi & 3, by = (wi >> 2) & 3, h = wi >> 4;
        ACC_INIT
        long row0 = (long)bx * 128, col0 = (long)by * 128;
        gemm128(g_wob, DIM, g_wvb, DIM, row0, col0, h * 64, h * 64 + 64, As, Bs, acc);
#pragma unroll
        for (int mi = 0; mi < 4; mi++)
#pragma unroll
            for (int ni = 0; ni < 4; ni++) {
                long col = col0 + wc * 64 + ni * 16 + fr;
#pragma unroll
                for (int r = 0; r < 4; r++) {
                    long row = row0 + wr * 64 + mi * 16 + fq * 4 + r;
                    g_wvo[row * 4096 + h * 512 + col] = __float2bfloat16(acc[mi][ni][r]);
                }
            }
    }
}

// ---------------- gather + fused transpose (conflict-free LDS, pipelined indices) ----------------
// 16 waves, 32 nodes per block; T layout [node][528]: lane writes 16B contiguous (0-conflict);
// transposed read banks (j*8+(f>>1))%32 all distinct (0-conflict). CSR indices for the next
// 8-edge chunk are vector-loaded BEFORE the current chunk's row loads (latency overlap).
__global__ __launch_bounds__(1024) void k_gather3() {
    __shared__ unsigned short T[32 * 528];       // 33 KB
    int bid = blockIdx.x;                        // 1024 blocks
    int gb = (bid & 7) * 128 + (bid >> 3);       // XCD swizzle: 8 graphs per XCD
    int b = gb >> 4, nt = gb & 15;
    int w = threadIdx.x >> 6, lane = threadIdx.x & 63;

#pragma unroll
    for (int k = 0; k < 2; k++) {
        int nl = w * 2 + k;                      // local node 0..31
        int node = b * 512 + nt * 32 + nl;

        bf16x8 sv = ((const bf16x8*)(g_xb + (long)node * DIM))[lane];
        float acc[8];
#pragma unroll
        for (int j = 0; j < 8; j++) acc[j] = bf2f((unsigned short)sv[j]);

        int e = g_off[node], e1 = g_off[node + 1];
        int4 i0, i1;
        bool have = (e + 8 <= e1);
        if (have) { i0 = *(const int4*)(g_csr + e); i1 = *(const int4*)(g_csr + e + 4); }
        while (have) {
            int n[8] = {i0.x, i0.y, i0.z, i0.w, i1.x, i1.y, i1.z, i1.w};
            e += 8;
            have = (e + 8 <= e1);
            if (have) { i0 = *(const int4*)(g_csr + e); i1 = *(const int4*)(g_csr + e + 4); }
            bf16x8 r[8];
#pragma unroll
            for (int q = 0; q < 8; q++)
                r[q] = ((const bf16x8*)(g_xb + (long)n[q] * DIM))[lane];
#pragma unroll
            for (int j = 0; j < 8; j++) {
                float s01 = bf2f((unsigned short)r[0][j]) + bf2f((unsigned short)r[1][j]);
                float s23 = bf2f((unsigned short)r[2][j]) + bf2f((unsigned short)r[3][j]);
                float s45 = bf2f((unsigned short)r[4][j]) + bf2f((unsigned short)r[5][j]);
                float s67 = bf2f((unsigned short)r[6][j]) + bf2f((unsigned short)r[7][j]);
                acc[j] += (s01 + s23) + (s45 + s67);
            }
        }
        for (; e < e1; e++) {
            bf16x8 r0 = ((const bf16x8*)(g_xb + (long)g_csr[e] * DIM))[lane];
#pragma unroll
            for (int j = 0; j < 8; j++) acc[j] += bf2f((unsigned short)r0[j]);
        }
        float dd = g_dinv[node];
        bf16x8 o;
#pragma unroll
        for (int j = 0; j < 8; j++) {
            bf16 t = __float2bfloat16(acc[j] * dd);
            o[j] = *(short*)&t;
        }
        ((bf16x8*)(g_agg + (long)node * DIM))[lane] = o;
        *(bf16x8*)&T[nl * 528 + lane * 8] = o;   // contiguous 16B: conflict-free
    }
    __syncthreads();

    // transposed write: thread t -> feature f = t>>1, half = t&1 (16 n-values, 32B)
    int f = threadIdx.x >> 1, half = threadIdx.x & 1;
    unsigned short tmp[16];
#pragma unroll
    for (int j = 0; j < 16; j++) tmp[j] = T[(half * 16 + j) * 528 + f];
    unsigned short* dst = (unsigned short*)g_aggT + ((long)b * 512 + f) * 512 + nt * 32 + half * 16;
    *(int4*)dst = *(int4*)tmp;
    *(int4*)(dst + 8) = *(int4*)(tmp + 8);
}

// scores (512 blk, graph-major XCD swizzle): C[hs][n] = QF . agg_b^T
__global__ __launch_bounds__(256) void k_score() {
    __shared__ bf16 As[2][128 * 32];
    __shared__ bf16 Bs[2][128 * 32];
    int blk = blockIdx.x;
    int b = blk & 63, bx = (blk >> 6) & 1, by = blk >> 7;
    ACC_INIT
    long row0 = (long)bx * 128, col0 = (long)by * 128;
    gemm128(g_qf, DIM, g_agg + (long)b * (MAXN * DIM), DIM, row0, col0, 0, DIM, As, Bs, acc);
    bf16* out = g_sc + (long)b * (256 * MAXN);
#pragma unroll
    for (int mi = 0; mi < 4; mi++)
#pragma unroll
        for (int ni = 0; ni < 4; ni++) {
            long col = col0 + wc * 64 + ni * 16 + fr;
#pragma unroll
            for (int r = 0; r < 4; r++) {
                long row = row0 + wr * 64 + mi * 16 + fq * 4 + r;
                out[row * MAXN + col] = __float2bfloat16(acc[mi][ni][r]);
            }
        }
}

// in-place row softmax on g_sc (16384 rows of 512)
__global__ __launch_bounds__(256) void k_soft() {
    int w = threadIdx.x >> 6, lane = threadIdx.x & 63;
    unsigned short* base = (unsigned short*)g_sc + ((long)blockIdx.x * 16 + w * 4) * MAXN;
#pragma unroll
    for (int r = 0; r < 4; r++) {
        unsigned short* row = base + (long)r * MAXN;
        float v[8]; float m = -1e30f;
#pragma unroll
        for (int k = 0; k < 8; k++) { v[k] = bf2f(row[lane + 64 * k]); m = fmaxf(m, v[k]); }
#pragma unroll
        for (int o = 32; o > 0; o >>= 1) m = fmaxf(m, __shfl_xor(m, o));
        float sum = 0.f;
#pragma unroll
        for (int k = 0; k < 8; k++) { v[k] = __expf(v[k] - m); sum += v[k]; }
#pragma unroll
        for (int o = 32; o > 0; o >>= 1) sum += __shfl_xor(sum, o);
        float inv = 1.0f / sum;
#pragma unroll
        for (int k = 0; k < 8; k++) {
            bf16 t = __float2bfloat16(v[k] * inv);
            row[lane + 64 * k] = *(unsigned short*)&t;
        }
    }
}

// ctxpre: per (b,dh): C[hs][d] = P_b[hs][:] . aggT_b[dh*256+d][:]  (graph-major swizzle)
__global__ __launch_bounds__(256) void k_pvg() {
    __shared__ bf16 As[2][128 * 32];
    __shared__ bf16 Bs[2][128 * 32];
    int blk = blockIdx.x;
    int b = blk & 63, bx = (blk >> 6) & 1, by = (blk >> 7) & 1, dh = blk >> 8;
    ACC_INIT
    long row0 = (long)bx * 128, col0 = (long)by * 128;
    gemm128(g_sc + (long)b * (256 * MAXN), MAXN,
            g_aggT + (long)b * (DIM * MAXN) + (long)dh * (256 * MAXN), MAXN,
            row0, col0, 0, MAXN, As, Bs, acc);
#pragma unroll
    for (int mi = 0; mi < 4; mi++)
#pragma unroll
        for (int ni = 0; ni < 4; ni++) {
            long col = col0 + wc * 64 + ni * 16 + fr;
#pragma unroll
            for (int r = 0; r < 4; r++) {
                long row = row0 + wr * 64 + mi * 16 + fq * 4 + r;   // hs
                g_cp[((long)b * NS + (row & 31)) * 4096 + (row >> 5) * 512 + dh * 256 + col] =
                    __float2bfloat16(acc[mi][ni][r]);
            }
        }
}

// attn_out partials: A=g_cp [2048][4096], Bt=g_wvo [512][4096], 4-way split-K
__global__ __launch_bounds__(256) void k_vo() {
    __shared__ bf16 As[2][128 * 32];
    __shared__ bf16 Bs[2][128 * 32];
    ACC_INIT
    int z = blockIdx.z;
    long row0 = (long)blockIdx.x * 128, col0 = (long)blockIdx.y * 128;
    gemm128(g_cp, 4096, g_wvo, 4096, row0, col0, z * 1024, z * 1024 + 1024, As, Bs, acc);
    float* out = g_part + (long)z * MP;
#pragma unroll
    for (int mi = 0; mi < 4; mi++)
#pragma unroll
        for (int ni = 0; ni < 4; ni++) {
            long col = col0 + wc * 64 + ni * 16 + fr;
#pragma unroll
            for (int r = 0; r < 4; r++) {
                long row = row0 + wr * 64 + mi * 16 + fq * 4 + r;
                out[row * DIM + col] = acc[mi][ni][r];
            }
        }
}

// FFN partials: A=g_h1b [2048][512], Bt=g_wffT [512][512], 4-way split-K
__global__ __launch_bounds__(256) void k_ffn() {
    __shared__ bf16 As[2][128 * 32];
    __shared__ bf16 Bs[2][128 * 32];
    ACC_INIT
    int z = blockIdx.z;
    long row0 = (long)blockIdx.x * 128, col0 = (long)blockIdx.y * 128;
    gemm128(g_h1b, DIM, g_wffT, DIM, row0, col0, z * 128, z * 128 + 128, As, Bs, acc);
    float* out = g_part + (long)z * MP;
#pragma unroll
    for (int mi = 0; mi < 4; mi++)
#pragma unroll
        for (int ni = 0; ni < 4; ni++) {
            long col = col0 + wc * 64 + ni * 16 + fr;
#pragma unroll
            for (int r = 0; r < 4; r++) {
                long row = row0 + wr * 64 + mi * 16 + fq * 4 + r;
                out[row * DIM + col] = acc[mi][ni][r];
            }
        }
}

// ---------------- layernorms (fused split-K reduction + bias) ----------------
__device__ inline float blockReduceSum(float v, float* red, int tid) {
#pragma unroll
    for (int o = 32; o > 0; o >>= 1) v += __shfl_xor(v, o);
    __syncthreads();
    if ((tid & 63) == 0) red[tid >> 6] = v;
    __syncthreads();
    return red[0] + red[1] + red[2] + red[3];
}

__global__ __launch_bounds__(256) void k_ln1(const float* __restrict__ seed,
                                             const float* __restrict__ gamma,
                                             const float* __restrict__ beta) {
    __shared__ float red[4];
    int r = blockIdx.x, t = threadIdx.x;
    int s = r & 31;
    long base = (long)r * DIM;
    float v0 = seed[s * DIM + t] + g_bvo[t];
    float v1 = seed[s * DIM + 256 + t] + g_bvo[256 + t];
#pragma unroll
    for (int z = 0; z < 4; z++) {
        v0 += g_part[(long)z * MP + base + t];
        v1 += g_part[(long)z * MP + base + 256 + t];
    }
    float mean = blockReduceSum(v0 + v1, red, t) * (1.0f / DIM);
    float d0 = v0 - mean, d1 = v1 - mean;
    float var = blockReduceSum(d0 * d0 + d1 * d1, red, t) * (1.0f / DIM);
    float ri = rsqrtf(var + 1e-5f);
    float o0 = d0 * ri * gamma[t] + beta[t];
    float o1 = d1 * ri * gamma[256 + t] + beta[256 + t];
    g_h1[base + t] = o0; g_h1[base + 256 + t] = o1;
    g_h1b[base + t] = __float2bfloat16(o0);
    g_h1b[base + 256 + t] = __float2bfloat16(o1);
}

__global__ __launch_bounds__(256) void k_ln2(const float* __restrict__ gamma,
                                             const float* __restrict__ beta,
                                             const float* __restrict__ bff,
                                             float* __restrict__ out) {
    __shared__ float red[4];
    int r = blockIdx.x, t = threadIdx.x;
    long base = (long)r * DIM;
    float v0 = g_h1[base + t] + bff[t];
    float v1 = g_h1[base + 256 + t] + bff[256 + t];
#pragma unroll
    for (int z = 0; z < 4; z++) {
        v0 += g_part[(long)z * MP + base + t];
        v1 += g_part[(long)z * MP + base + 256 + t];
    }
    float mean = blockReduceSum(v0 + v1, red, t) * (1.0f / DIM);
    float d0 = v0 - mean, d1 = v1 - mean;
    float var = blockReduceSum(d0 * d0 + d1 * d1, red, t) * (1.0f / DIM);
    float ri = rsqrtf(var + 1e-5f);
    out[base + t] = d0 * ri * gamma[t] + beta[t];
    out[base + 256 + t] = d1 * ri * gamma[256 + t] + beta[256 + t];
}

// ---------------- launch ----------------
extern "C" void kernel_launch(void* const* d_in, const int* in_sizes, int n_in,
                              void* d_out, int out_size, void* d_ws, size_t ws_size,
                              hipStream_t stream) {
    (void)in_sizes; (void)n_in; (void)out_size; (void)d_ws; (void)ws_size;
    const float* x    = (const float*)d_in[1];
    const int*   ei   = (const int*)d_in[2];
    const int*   esrc = ei;
    const int*   edst = ei + NE;
    const float* seed = (const float*)d_in[4];
    const float* Wk   = (const float*)d_in[5];
    const float* Wv   = (const float*)d_in[7];
    const float* bv   = (const float*)d_in[8];
    const float* Wq   = (const float*)d_in[9];
    const float* Wo   = (const float*)d_in[10];
    const float* bo   = (const float*)d_in[11];
    const float* Wff  = (const float*)d_in[12];
    const float* bff  = (const float*)d_in[13];
    const float* gh   = (const float*)d_in[14];
    const float* bh   = (const float*)d_in[15];
    const float* gz   = (const float*)d_in[16];
    const float* bz   = (const float*)d_in[17];
    float* out = (float*)d_out;

    k_hist    <<<NBLK, 1024, 0, stream>>>(edst);
    k_colscan <<<NN / 512, 256, 0, stream>>>();
    k_scan    <<<1, 1024, 0, stream>>>();
    k_prep    <<<450, 256, 0, stream>>>(seed, Wq, Wo, Wv, Wff, bo, bv);
    k_fillsort<<<NBLK, 1024, 0, stream>>>(esrc, edst);
    k_xbqf    <<<8832, 256, 0, stream>>>(x, Wk);
    k_gather3 <<<1024, 1024, 0, stream>>>();
    k_score   <<<512, 256, 0, stream>>>();
    k_soft    <<<1024, 256, 0, stream>>>();
    k_pvg     <<<512, 256, 0, stream>>>();
    k_vo      <<<dim3(16, 4, 4), 256, 0, stream>>>();
    k_ln1     <<<BN * NS, 256, 0, stream>>>(seed, gh, bh);
    k_ffn     <<<dim3(16, 4, 4), 256, 0, stream>>>();
    k_ln2     <<<BN * NS, 256, 0, stream>>>(gz, bz, bff, out);
}